// Round 1
// baseline (510.052 us; speedup 1.0000x reference)
//
#include <hip/hip_runtime.h>
#include <math.h>

#define BDIM 32
#define TDIM 128
#define HID 768
#define INP 256

// exp(-1/20); reference uses python-double constants rounded at f32 use sites.
#define ALPHA_F 0.9512294245007140f
#define DECAY_F 0.9512294245007140f
#define ETA_F 0.1f
// 0.2 * ETA
#define IKV_SCALE 0.02f

// ---------------------------------------------------------------------------
// K1: I[M=4096][N=1536] = X[4096][256] @ W[1536][256]^T   (fp32)
// ---------------------------------------------------------------------------
__global__ __launch_bounds__(256) void k1_gemm(const float* __restrict__ X,
                                               const float* __restrict__ W,
                                               float* __restrict__ I) {
    __shared__ float Xs[64][33];
    __shared__ float Ws[64][33];
    const int bm = blockIdx.x * 64;
    const int bn = blockIdx.y * 64;
    const int tid = threadIdx.x;
    const int tx = tid & 15;
    const int ty = tid >> 4;
    float acc[4][4] = {};

    for (int k0 = 0; k0 < INP; k0 += 32) {
        // stage X tile (64x32) and W tile (64x32); float4 global loads,
        // scalar LDS stores (stride 33 keeps reads conflict-light).
        const int r = tid >> 3;          // 0..31
        const int c = (tid & 7) * 4;     // 0..28
        float4 x0 = *(const float4*)&X[(size_t)(bm + r) * INP + k0 + c];
        float4 x1 = *(const float4*)&X[(size_t)(bm + r + 32) * INP + k0 + c];
        float4 w0 = *(const float4*)&W[(size_t)(bn + r) * INP + k0 + c];
        float4 w1 = *(const float4*)&W[(size_t)(bn + r + 32) * INP + k0 + c];
        Xs[r][c + 0] = x0.x; Xs[r][c + 1] = x0.y; Xs[r][c + 2] = x0.z; Xs[r][c + 3] = x0.w;
        Xs[r + 32][c + 0] = x1.x; Xs[r + 32][c + 1] = x1.y; Xs[r + 32][c + 2] = x1.z; Xs[r + 32][c + 3] = x1.w;
        Ws[r][c + 0] = w0.x; Ws[r][c + 1] = w0.y; Ws[r][c + 2] = w0.z; Ws[r][c + 3] = w0.w;
        Ws[r + 32][c + 0] = w1.x; Ws[r + 32][c + 1] = w1.y; Ws[r + 32][c + 2] = w1.z; Ws[r + 32][c + 3] = w1.w;
        __syncthreads();

        for (int kk = 0; kk < 32; ++kk) {
            float a[4], b[4];
#pragma unroll
            for (int i = 0; i < 4; ++i) a[i] = Xs[ty + 16 * i][kk];
#pragma unroll
            for (int j = 0; j < 4; ++j) b[j] = Ws[tx + 16 * j][kk];
#pragma unroll
            for (int i = 0; i < 4; ++i)
#pragma unroll
                for (int j = 0; j < 4; ++j)
                    acc[i][j] += a[i] * b[j];
        }
        __syncthreads();
    }
#pragma unroll
    for (int i = 0; i < 4; ++i)
#pragma unroll
        for (int j = 0; j < 4; ++j)
            I[(size_t)(bm + ty + 16 * i) * (2 * HID) + bn + tx + 16 * j] = acc[i][j];
}

// ---------------------------------------------------------------------------
// K2: key path — per (b,h) scalar chain over t. Fully parallel.
//     kv = a*kv + (1-a)*ik; key_o = tanh(kv); ktr = d*ktr + (1-d)*key_o
// ---------------------------------------------------------------------------
__global__ __launch_bounds__(256) void k2_key(const float* __restrict__ I,
                                              float* __restrict__ keys,
                                              float* __restrict__ ktr_g) {
    const int gid = blockIdx.x * 256 + threadIdx.x;   // 0 .. 32*768-1
    const int b = gid / HID;
    const int h = gid % HID;
    float kv = 0.f, kt = 0.f;
    for (int t = 0; t < TDIM; ++t) {
        const size_t row = (size_t)(b * TDIM + t);
        float ik = I[row * (2 * HID) + h];
        kv = ALPHA_F * kv + (1.f - ALPHA_F) * ik;
        float ko = tanhf(kv);
        keys[row * HID + h] = ko;
        kt = DECAY_F * kt + (1.f - DECAY_F) * ko;
        ktr_g[row * HID + h] = kt;
    }
}

// ---------------------------------------------------------------------------
// K3: C[b][t][s] = sum_h keys[b][t][h] * ktr[b][s][h]
//     one block per (b, t-quarter): 32x128 outputs, 256 threads, 4x4 each
// ---------------------------------------------------------------------------
__global__ __launch_bounds__(256) void k3_cmat(const float* __restrict__ keys,
                                               const float* __restrict__ ktr_g,
                                               float* __restrict__ Cm) {
    __shared__ float Ts[32][33];
    __shared__ float Ss[128][33];
    const int b = blockIdx.x;
    const int tq = blockIdx.y;
    const int tid = threadIdx.x;
    const int txs = tid & 31;   // s block: s = txs*4 + jj
    const int tyt = tid >> 5;   // t block: t = tq*32 + tyt*4 + i
    float acc[4][4] = {};

    for (int k0 = 0; k0 < HID; k0 += 32) {
        const int r = tid >> 3;
        const int c = (tid & 7) * 4;
        float4 kv4 = *(const float4*)&keys[(size_t)(b * TDIM + tq * 32 + r) * HID + k0 + c];
        Ts[r][c + 0] = kv4.x; Ts[r][c + 1] = kv4.y; Ts[r][c + 2] = kv4.z; Ts[r][c + 3] = kv4.w;
#pragma unroll
        for (int u = 0; u < 4; ++u) {
            const int rr = r + u * 32;
            float4 s4 = *(const float4*)&ktr_g[(size_t)(b * TDIM + rr) * HID + k0 + c];
            Ss[rr][c + 0] = s4.x; Ss[rr][c + 1] = s4.y; Ss[rr][c + 2] = s4.z; Ss[rr][c + 3] = s4.w;
        }
        __syncthreads();

        for (int kk = 0; kk < 32; ++kk) {
            float a[4], bv[4];
#pragma unroll
            for (int i = 0; i < 4; ++i) a[i] = Ts[tyt * 4 + i][kk];
#pragma unroll
            for (int j = 0; j < 4; ++j) bv[j] = Ss[txs * 4 + j][kk];
#pragma unroll
            for (int i = 0; i < 4; ++i)
#pragma unroll
                for (int j = 0; j < 4; ++j)
                    acc[i][j] += a[i] * bv[j];
        }
        __syncthreads();
    }
#pragma unroll
    for (int i = 0; i < 4; ++i) {
        const int t = tq * 32 + tyt * 4 + i;
#pragma unroll
        for (int j = 0; j < 4; ++j) {
            const int s = txs * 4 + j;
            Cm[((size_t)b * TDIM + t) * TDIM + s] = acc[i][j];
        }
    }
}

// ---------------------------------------------------------------------------
// K4: value recurrence. One 64-thread block per (b, 64-wide h chunk).
//     ikv_t[h] = sum_{s<t} C[b][t][s] * vtr_s[h]  (vtr history in LDS)
//     vv = a*vv + (1-a)*(iv + 0.02*ikv); val=tanh(vv); vtr = d*vtr+(1-d)*val
// ---------------------------------------------------------------------------
__global__ __launch_bounds__(64) void k4_value(const float* __restrict__ I,
                                               const float* __restrict__ Cm,
                                               float* __restrict__ vals,
                                               float* __restrict__ vtr_g) {
    __shared__ float hist[TDIM][64];
    __shared__ float crow[TDIM];
    const int b = blockIdx.x / 12;
    const int h0 = (blockIdx.x % 12) * 64;
    const int j = threadIdx.x;
    const int h = h0 + j;

    float vv = 0.f, vtr = 0.f;
    for (int t = 0; t < TDIM; ++t) {
        // stage C row t (coefficients c[s], s<t), shared across lanes
        for (int s = j; s < t; s += 64)
            crow[s] = Cm[((size_t)b * TDIM + t) * TDIM + s];
        __syncthreads();

        float ikv0 = 0.f, ikv1 = 0.f, ikv2 = 0.f, ikv3 = 0.f;
        int s = 0;
        for (; s + 4 <= t; s += 4) {
            float4 c4 = *(const float4*)&crow[s];
            ikv0 += c4.x * hist[s + 0][j];
            ikv1 += c4.y * hist[s + 1][j];
            ikv2 += c4.z * hist[s + 2][j];
            ikv3 += c4.w * hist[s + 3][j];
        }
        for (; s < t; ++s) ikv0 += crow[s] * hist[s][j];
        const float ikv = (ikv0 + ikv1) + (ikv2 + ikv3);

        const size_t row = (size_t)(b * TDIM + t);
        const float iv = I[row * (2 * HID) + HID + h];
        vv = ALPHA_F * vv + (1.f - ALPHA_F) * (iv + IKV_SCALE * ikv);
        const float val = tanhf(vv);
        vals[row * HID + h] = val;
        vtr = DECAY_F * vtr + (1.f - DECAY_F) * val;
        hist[t][j] = vtr;
        vtr_g[row * HID + h] = vtr;
        __syncthreads();
    }
}

// ---------------------------------------------------------------------------
// K5: mem[b][i][j] = ETA * sum_t vtr[b][t][i] * ktr[b][t][j]
//     batched 768x768 GEMM, K=128. 64x64 tile per block, 4x4 per thread.
// ---------------------------------------------------------------------------
__global__ __launch_bounds__(256) void k5_mem(const float* __restrict__ vtr_g,
                                              const float* __restrict__ ktr_g,
                                              float* __restrict__ mem) {
    __shared__ float Vs[16][68];
    __shared__ float Ks[16][68];
    const int b = blockIdx.z;
    const int i0 = blockIdx.y * 64;
    const int j0 = blockIdx.x * 64;
    const int tid = threadIdx.x;
    const int tx = tid & 15;
    const int ty = tid >> 4;
    float acc[4][4] = {};

    for (int t0 = 0; t0 < TDIM; t0 += 16) {
        const int tt = tid >> 4;            // 0..15 rows
        const int c4 = (tid & 15) * 4;      // 0..60 cols
        *(float4*)&Vs[tt][c4] = *(const float4*)&vtr_g[((size_t)b * TDIM + t0 + tt) * HID + i0 + c4];
        *(float4*)&Ks[tt][c4] = *(const float4*)&ktr_g[((size_t)b * TDIM + t0 + tt) * HID + j0 + c4];
        __syncthreads();

        for (int k = 0; k < 16; ++k) {
            float4 a = *(const float4*)&Vs[k][ty * 4];
            float4 bv = *(const float4*)&Ks[k][tx * 4];
            acc[0][0] += a.x * bv.x; acc[0][1] += a.x * bv.y; acc[0][2] += a.x * bv.z; acc[0][3] += a.x * bv.w;
            acc[1][0] += a.y * bv.x; acc[1][1] += a.y * bv.y; acc[1][2] += a.y * bv.z; acc[1][3] += a.y * bv.w;
            acc[2][0] += a.z * bv.x; acc[2][1] += a.z * bv.y; acc[2][2] += a.z * bv.z; acc[2][3] += a.z * bv.w;
            acc[3][0] += a.w * bv.x; acc[3][1] += a.w * bv.y; acc[3][2] += a.w * bv.z; acc[3][3] += a.w * bv.w;
        }
        __syncthreads();
    }
#pragma unroll
    for (int i = 0; i < 4; ++i) {
        float4 o;
        o.x = ETA_F * acc[i][0];
        o.y = ETA_F * acc[i][1];
        o.z = ETA_F * acc[i][2];
        o.w = ETA_F * acc[i][3];
        *(float4*)&mem[((size_t)b * HID + i0 + ty * 4 + i) * HID + j0 + tx * 4] = o;
    }
}

// ---------------------------------------------------------------------------
extern "C" void kernel_launch(void* const* d_in, const int* in_sizes, int n_in,
                              void* d_out, int out_size, void* d_ws, size_t ws_size,
                              hipStream_t stream) {
    (void)in_sizes; (void)n_in; (void)out_size; (void)ws_size;
    const float* x = (const float*)d_in[0];   // (32,128,256)
    const float* W = (const float*)d_in[1];   // (1536,256)

    float* out = (float*)d_out;
    float* mem_out = out;                                        // 32*768*768
    float* keys_out = out + (size_t)BDIM * HID * HID;            // 32*128*768
    float* vals_out = keys_out + (size_t)BDIM * TDIM * HID;      // 32*128*768

    // workspace: i(25.2MB) + ktr(12.6) + vtr(12.6) + C(2) = 52.4 MB
    float* i_buf = (float*)d_ws;                                 // (B*T, 1536)
    float* ktr_g = i_buf + (size_t)BDIM * TDIM * 2 * HID;        // (B*T, 768)
    float* vtr_g = ktr_g + (size_t)BDIM * TDIM * HID;            // (B*T, 768)
    float* C_buf = vtr_g + (size_t)BDIM * TDIM * HID;            // (B, T, T)

    hipLaunchKernelGGL(k1_gemm, dim3(64, 24), dim3(256), 0, stream, x, W, i_buf);
    hipLaunchKernelGGL(k2_key, dim3(96), dim3(256), 0, stream, i_buf, keys_out, ktr_g);
    hipLaunchKernelGGL(k3_cmat, dim3(32, 4), dim3(256), 0, stream, keys_out, ktr_g, C_buf);
    hipLaunchKernelGGL(k4_value, dim3(384), dim3(64), 0, stream, i_buf, C_buf, vals_out, vtr_g);
    hipLaunchKernelGGL(k5_mem, dim3(12, 12, 32), dim3(256), 0, stream, vtr_g, ktr_g, mem_out);
}

// Round 3
// 436.929 us; speedup vs baseline: 1.1674x; 1.1674x over previous
//
#include <hip/hip_runtime.h>
#include <math.h>

#define BDIM 32
#define TDIM 128
#define HID 768
#define INP 256

// exp(-1/20); reference uses python-double constants rounded at f32 use sites.
#define ALPHA_F 0.9512294245007140f
#define DECAY_F 0.9512294245007140f
#define ETA_F 0.1f
// 0.2 * ETA
#define IKV_SCALE 0.02f

// ---------------------------------------------------------------------------
// K1: I[M=4096][N=1536] = X[4096][256] @ W[1536][256]^T   (fp32)
// ---------------------------------------------------------------------------
__global__ __launch_bounds__(256) void k1_gemm(const float* __restrict__ X,
                                               const float* __restrict__ W,
                                               float* __restrict__ I) {
    __shared__ float Xs[64][33];
    __shared__ float Ws[64][33];
    const int bm = blockIdx.x * 64;
    const int bn = blockIdx.y * 64;
    const int tid = threadIdx.x;
    const int tx = tid & 15;
    const int ty = tid >> 4;
    float acc[4][4] = {};

    for (int k0 = 0; k0 < INP; k0 += 32) {
        const int r = tid >> 3;          // 0..31
        const int c = (tid & 7) * 4;     // 0..28
        float4 x0 = *(const float4*)&X[(size_t)(bm + r) * INP + k0 + c];
        float4 x1 = *(const float4*)&X[(size_t)(bm + r + 32) * INP + k0 + c];
        float4 w0 = *(const float4*)&W[(size_t)(bn + r) * INP + k0 + c];
        float4 w1 = *(const float4*)&W[(size_t)(bn + r + 32) * INP + k0 + c];
        Xs[r][c + 0] = x0.x; Xs[r][c + 1] = x0.y; Xs[r][c + 2] = x0.z; Xs[r][c + 3] = x0.w;
        Xs[r + 32][c + 0] = x1.x; Xs[r + 32][c + 1] = x1.y; Xs[r + 32][c + 2] = x1.z; Xs[r + 32][c + 3] = x1.w;
        Ws[r][c + 0] = w0.x; Ws[r][c + 1] = w0.y; Ws[r][c + 2] = w0.z; Ws[r][c + 3] = w0.w;
        Ws[r + 32][c + 0] = w1.x; Ws[r + 32][c + 1] = w1.y; Ws[r + 32][c + 2] = w1.z; Ws[r + 32][c + 3] = w1.w;
        __syncthreads();

        for (int kk = 0; kk < 32; ++kk) {
            float a[4], b[4];
#pragma unroll
            for (int i = 0; i < 4; ++i) a[i] = Xs[ty + 16 * i][kk];
#pragma unroll
            for (int j = 0; j < 4; ++j) b[j] = Ws[tx + 16 * j][kk];
#pragma unroll
            for (int i = 0; i < 4; ++i)
#pragma unroll
                for (int j = 0; j < 4; ++j)
                    acc[i][j] += a[i] * b[j];
        }
        __syncthreads();
    }
#pragma unroll
    for (int i = 0; i < 4; ++i)
#pragma unroll
        for (int j = 0; j < 4; ++j)
            I[(size_t)(bm + ty + 16 * i) * (2 * HID) + bn + tx + 16 * j] = acc[i][j];
}

// ---------------------------------------------------------------------------
// K2: key path — per (b,h) scalar chain over t. Fully parallel.
// ---------------------------------------------------------------------------
__global__ __launch_bounds__(256) void k2_key(const float* __restrict__ I,
                                              float* __restrict__ keys,
                                              float* __restrict__ ktr_g) {
    const int gid = blockIdx.x * 256 + threadIdx.x;   // 0 .. 32*768-1
    const int b = gid / HID;
    const int h = gid % HID;
    float kv = 0.f, kt = 0.f;
    for (int t = 0; t < TDIM; ++t) {
        const size_t row = (size_t)(b * TDIM + t);
        float ik = I[row * (2 * HID) + h];
        kv = ALPHA_F * kv + (1.f - ALPHA_F) * ik;
        float ko = tanhf(kv);
        keys[row * HID + h] = ko;
        kt = DECAY_F * kt + (1.f - DECAY_F) * ko;
        ktr_g[row * HID + h] = kt;
    }
}

// ---------------------------------------------------------------------------
// K3: C[b][t][s] = sum_h keys[b][t][h] * ktr[b][s][h]
// ---------------------------------------------------------------------------
__global__ __launch_bounds__(256) void k3_cmat(const float* __restrict__ keys,
                                               const float* __restrict__ ktr_g,
                                               float* __restrict__ Cm) {
    __shared__ float Ts[32][33];
    __shared__ float Ss[128][33];
    const int b = blockIdx.x;
    const int tq = blockIdx.y;
    const int tid = threadIdx.x;
    const int txs = tid & 31;
    const int tyt = tid >> 5;
    float acc[4][4] = {};

    for (int k0 = 0; k0 < HID; k0 += 32) {
        const int r = tid >> 3;
        const int c = (tid & 7) * 4;
        float4 kv4 = *(const float4*)&keys[(size_t)(b * TDIM + tq * 32 + r) * HID + k0 + c];
        Ts[r][c + 0] = kv4.x; Ts[r][c + 1] = kv4.y; Ts[r][c + 2] = kv4.z; Ts[r][c + 3] = kv4.w;
#pragma unroll
        for (int u = 0; u < 4; ++u) {
            const int rr = r + u * 32;
            float4 s4 = *(const float4*)&ktr_g[(size_t)(b * TDIM + rr) * HID + k0 + c];
            Ss[rr][c + 0] = s4.x; Ss[rr][c + 1] = s4.y; Ss[rr][c + 2] = s4.z; Ss[rr][c + 3] = s4.w;
        }
        __syncthreads();

        for (int kk = 0; kk < 32; ++kk) {
            float a[4], bv[4];
#pragma unroll
            for (int i = 0; i < 4; ++i) a[i] = Ts[tyt * 4 + i][kk];
#pragma unroll
            for (int j = 0; j < 4; ++j) bv[j] = Ss[txs * 4 + j][kk];
#pragma unroll
            for (int i = 0; i < 4; ++i)
#pragma unroll
                for (int j = 0; j < 4; ++j)
                    acc[i][j] += a[i] * bv[j];
        }
        __syncthreads();
    }
#pragma unroll
    for (int i = 0; i < 4; ++i) {
        const int t = tq * 32 + tyt * 4 + i;
#pragma unroll
        for (int j = 0; j < 4; ++j) {
            const int s = txs * 4 + j;
            Cm[((size_t)b * TDIM + t) * TDIM + s] = acc[i][j];
        }
    }
}

// ---------------------------------------------------------------------------
// K4 v2: value recurrence, barrier-free steady state.
//   Block = 128 threads = one (b, 128-wide h chunk). Grid 6 x 32 = 192 blocks
//   -> 1 block/CU, all co-resident (128 KB LDS each).
//   Stage all of C[b] (64 KB) ONCE; hist column j is private to thread j, so
//   the t-loop needs no __syncthreads at all. The iv global load is
//   software-pipelined one iteration ahead so its latency hides under the dot.
// ---------------------------------------------------------------------------
__global__ __launch_bounds__(128) void k4_value(const float* __restrict__ I,
                                                const float* __restrict__ Cm,
                                                float* __restrict__ vals,
                                                float* __restrict__ vtr_g) {
    __shared__ float Cs[TDIM][TDIM];      // 64 KB, broadcast reads
    __shared__ float hist[TDIM][128];     // 64 KB, column-private
    const int b = blockIdx.y;
    const int h0 = blockIdx.x * 128;
    const int j = threadIdx.x;
    const int h = h0 + j;

    // stage C[b] cooperatively: 16384 floats, 32 float4 per thread, coalesced
    {
        const float* Cb = &Cm[(size_t)b * TDIM * TDIM];
        float* Cf = &Cs[0][0];
#pragma unroll
        for (int u = 0; u < 32; ++u) {
            const int idx = (u * 128 + j) * 4;
            *(float4*)&Cf[idx] = *(const float4*)&Cb[idx];
        }
    }
    __syncthreads();

    const float* Ibase = &I[(size_t)b * TDIM * (2 * HID) + HID + h];
    float vv = 0.f, vtr = 0.f;
    float iv = Ibase[0];
    for (int t = 0; t < TDIM; ++t) {
        // prefetch next iv; waitcnt lands after the dot loop below
        float iv_next = (t + 1 < TDIM) ? Ibase[(size_t)(t + 1) * (2 * HID)] : 0.f;

        float ikv0 = 0.f, ikv1 = 0.f, ikv2 = 0.f, ikv3 = 0.f;
        const float* crow = &Cs[t][0];
        int s = 0;
        for (; s + 4 <= t; s += 4) {
            float4 c4 = *(const float4*)&crow[s];   // lane-uniform: broadcast
            ikv0 += c4.x * hist[s + 0][j];
            ikv1 += c4.y * hist[s + 1][j];
            ikv2 += c4.z * hist[s + 2][j];
            ikv3 += c4.w * hist[s + 3][j];
        }
        for (; s < t; ++s) ikv0 += crow[s] * hist[s][j];
        const float ikv = (ikv0 + ikv1) + (ikv2 + ikv3);

        const size_t row = (size_t)(b * TDIM + t);
        vv = ALPHA_F * vv + (1.f - ALPHA_F) * (iv + IKV_SCALE * ikv);
        const float val = tanhf(vv);
        vals[row * HID + h] = val;
        vtr = DECAY_F * vtr + (1.f - DECAY_F) * val;
        hist[t][j] = vtr;                 // own column; no barrier needed
        vtr_g[row * HID + h] = vtr;
        iv = iv_next;
    }
}

// ---------------------------------------------------------------------------
// K5: mem[b][i][j] = ETA * sum_t vtr[b][t][i] * ktr[b][t][j]
// ---------------------------------------------------------------------------
__global__ __launch_bounds__(256) void k5_mem(const float* __restrict__ vtr_g,
                                              const float* __restrict__ ktr_g,
                                              float* __restrict__ mem) {
    __shared__ float Vs[16][68];
    __shared__ float Ks[16][68];
    const int b = blockIdx.z;
    const int i0 = blockIdx.y * 64;
    const int j0 = blockIdx.x * 64;
    const int tid = threadIdx.x;
    const int tx = tid & 15;
    const int ty = tid >> 4;
    float acc[4][4] = {};

    for (int t0 = 0; t0 < TDIM; t0 += 16) {
        const int tt = tid >> 4;
        const int c4 = (tid & 15) * 4;
        *(float4*)&Vs[tt][c4] = *(const float4*)&vtr_g[((size_t)b * TDIM + t0 + tt) * HID + i0 + c4];
        *(float4*)&Ks[tt][c4] = *(const float4*)&ktr_g[((size_t)b * TDIM + t0 + tt) * HID + j0 + c4];
        __syncthreads();

        for (int k = 0; k < 16; ++k) {
            float4 a = *(const float4*)&Vs[k][ty * 4];
            float4 bv = *(const float4*)&Ks[k][tx * 4];
            acc[0][0] += a.x * bv.x; acc[0][1] += a.x * bv.y; acc[0][2] += a.x * bv.z; acc[0][3] += a.x * bv.w;
            acc[1][0] += a.y * bv.x; acc[1][1] += a.y * bv.y; acc[1][2] += a.y * bv.z; acc[1][3] += a.y * bv.w;
            acc[2][0] += a.z * bv.x; acc[2][1] += a.z * bv.y; acc[2][2] += a.z * bv.z; acc[2][3] += a.z * bv.w;
            acc[3][0] += a.w * bv.x; acc[3][1] += a.w * bv.y; acc[3][2] += a.w * bv.z; acc[3][3] += a.w * bv.w;
        }
        __syncthreads();
    }
#pragma unroll
    for (int i = 0; i < 4; ++i) {
        float4 o;
        o.x = ETA_F * acc[i][0];
        o.y = ETA_F * acc[i][1];
        o.z = ETA_F * acc[i][2];
        o.w = ETA_F * acc[i][3];
        *(float4*)&mem[((size_t)b * HID + i0 + ty * 4 + i) * HID + j0 + tx * 4] = o;
    }
}

// ---------------------------------------------------------------------------
extern "C" void kernel_launch(void* const* d_in, const int* in_sizes, int n_in,
                              void* d_out, int out_size, void* d_ws, size_t ws_size,
                              hipStream_t stream) {
    (void)in_sizes; (void)n_in; (void)out_size; (void)ws_size;
    const float* x = (const float*)d_in[0];   // (32,128,256)
    const float* W = (const float*)d_in[1];   // (1536,256)

    float* out = (float*)d_out;
    float* mem_out = out;                                        // 32*768*768
    float* keys_out = out + (size_t)BDIM * HID * HID;            // 32*128*768
    float* vals_out = keys_out + (size_t)BDIM * TDIM * HID;      // 32*128*768

    float* i_buf = (float*)d_ws;                                 // (B*T, 1536)
    float* ktr_g = i_buf + (size_t)BDIM * TDIM * 2 * HID;        // (B*T, 768)
    float* vtr_g = ktr_g + (size_t)BDIM * TDIM * HID;            // (B*T, 768)
    float* C_buf = vtr_g + (size_t)BDIM * TDIM * HID;            // (B, T, T)

    hipLaunchKernelGGL(k1_gemm, dim3(64, 24), dim3(256), 0, stream, x, W, i_buf);
    hipLaunchKernelGGL(k2_key, dim3(96), dim3(256), 0, stream, i_buf, keys_out, ktr_g);
    hipLaunchKernelGGL(k3_cmat, dim3(32, 4), dim3(256), 0, stream, keys_out, ktr_g, C_buf);
    hipLaunchKernelGGL(k4_value, dim3(6, 32), dim3(128), 0, stream, i_buf, C_buf, vals_out, vtr_g);
    hipLaunchKernelGGL(k5_mem, dim3(12, 12, 32), dim3(256), 0, stream, vtr_g, ktr_g, mem_out);
}

// Round 4
// 361.308 us; speedup vs baseline: 1.4117x; 1.2093x over previous
//
#include <hip/hip_runtime.h>
#include <math.h>

#define BDIM 32
#define TDIM 128
#define HID 768
#define INP 256

// exp(-1/20); reference uses python-double constants rounded at f32 use sites.
#define ALPHA_F 0.9512294245007140f
#define DECAY_F 0.9512294245007140f
#define ETA_F 0.1f
// 0.2 * ETA
#define IKV_SCALE 0.02f

// ---------------------------------------------------------------------------
// K1: I[M=4096][N=1536] = X[4096][256] @ W[1536][256]^T   (fp32)
// ---------------------------------------------------------------------------
__global__ __launch_bounds__(256) void k1_gemm(const float* __restrict__ X,
                                               const float* __restrict__ W,
                                               float* __restrict__ I) {
    __shared__ float Xs[64][33];
    __shared__ float Ws[64][33];
    const int bm = blockIdx.x * 64;
    const int bn = blockIdx.y * 64;
    const int tid = threadIdx.x;
    const int tx = tid & 15;
    const int ty = tid >> 4;
    float acc[4][4] = {};

    for (int k0 = 0; k0 < INP; k0 += 32) {
        const int r = tid >> 3;          // 0..31
        const int c = (tid & 7) * 4;     // 0..28
        float4 x0 = *(const float4*)&X[(size_t)(bm + r) * INP + k0 + c];
        float4 x1 = *(const float4*)&X[(size_t)(bm + r + 32) * INP + k0 + c];
        float4 w0 = *(const float4*)&W[(size_t)(bn + r) * INP + k0 + c];
        float4 w1 = *(const float4*)&W[(size_t)(bn + r + 32) * INP + k0 + c];
        Xs[r][c + 0] = x0.x; Xs[r][c + 1] = x0.y; Xs[r][c + 2] = x0.z; Xs[r][c + 3] = x0.w;
        Xs[r + 32][c + 0] = x1.x; Xs[r + 32][c + 1] = x1.y; Xs[r + 32][c + 2] = x1.z; Xs[r + 32][c + 3] = x1.w;
        Ws[r][c + 0] = w0.x; Ws[r][c + 1] = w0.y; Ws[r][c + 2] = w0.z; Ws[r][c + 3] = w0.w;
        Ws[r + 32][c + 0] = w1.x; Ws[r + 32][c + 1] = w1.y; Ws[r + 32][c + 2] = w1.z; Ws[r + 32][c + 3] = w1.w;
        __syncthreads();

        for (int kk = 0; kk < 32; ++kk) {
            float a[4], b[4];
#pragma unroll
            for (int i = 0; i < 4; ++i) a[i] = Xs[ty + 16 * i][kk];
#pragma unroll
            for (int j = 0; j < 4; ++j) b[j] = Ws[tx + 16 * j][kk];
#pragma unroll
            for (int i = 0; i < 4; ++i)
#pragma unroll
                for (int j = 0; j < 4; ++j)
                    acc[i][j] += a[i] * b[j];
        }
        __syncthreads();
    }
#pragma unroll
    for (int i = 0; i < 4; ++i)
#pragma unroll
        for (int j = 0; j < 4; ++j)
            I[(size_t)(bm + ty + 16 * i) * (2 * HID) + bn + tx + 16 * j] = acc[i][j];
}

// ---------------------------------------------------------------------------
// K2: key path — per (b,h) scalar chain over t, loads pipelined 8-deep
//     (the loads are address-independent of the recurrence).
// ---------------------------------------------------------------------------
__global__ __launch_bounds__(256) void k2_key(const float* __restrict__ I,
                                              float* __restrict__ keys,
                                              float* __restrict__ ktr_g) {
    const int gid = blockIdx.x * 256 + threadIdx.x;   // 0 .. 32*768-1
    const int b = gid / HID;
    const int h = gid % HID;
    const float* Ib = I + (size_t)b * TDIM * (2 * HID) + h;
    float* kb = keys + (size_t)b * TDIM * HID + h;
    float* tb = ktr_g + (size_t)b * TDIM * HID + h;
    float kv = 0.f, kt = 0.f;
    for (int t = 0; t < TDIM; t += 8) {
        float ik[8];
#pragma unroll
        for (int q = 0; q < 8; ++q) ik[q] = Ib[(size_t)(t + q) * (2 * HID)];
#pragma unroll
        for (int q = 0; q < 8; ++q) {
            kv = ALPHA_F * kv + (1.f - ALPHA_F) * ik[q];
            float ko = tanhf(kv);
            kb[(size_t)(t + q) * HID] = ko;
            kt = DECAY_F * kt + (1.f - DECAY_F) * ko;
            tb[(size_t)(t + q) * HID] = kt;
        }
    }
}

// ---------------------------------------------------------------------------
// K3: C[b][t][s] = sum_h keys[b][t][h] * ktr[b][s][h]
// ---------------------------------------------------------------------------
__global__ __launch_bounds__(256) void k3_cmat(const float* __restrict__ keys,
                                               const float* __restrict__ ktr_g,
                                               float* __restrict__ Cm) {
    __shared__ float Ts[32][33];
    __shared__ float Ss[128][33];
    const int b = blockIdx.x;
    const int tq = blockIdx.y;
    const int tid = threadIdx.x;
    const int txs = tid & 31;
    const int tyt = tid >> 5;
    float acc[4][4] = {};

    for (int k0 = 0; k0 < HID; k0 += 32) {
        const int r = tid >> 3;
        const int c = (tid & 7) * 4;
        float4 kv4 = *(const float4*)&keys[(size_t)(b * TDIM + tq * 32 + r) * HID + k0 + c];
        Ts[r][c + 0] = kv4.x; Ts[r][c + 1] = kv4.y; Ts[r][c + 2] = kv4.z; Ts[r][c + 3] = kv4.w;
#pragma unroll
        for (int u = 0; u < 4; ++u) {
            const int rr = r + u * 32;
            float4 s4 = *(const float4*)&ktr_g[(size_t)(b * TDIM + rr) * HID + k0 + c];
            Ss[rr][c + 0] = s4.x; Ss[rr][c + 1] = s4.y; Ss[rr][c + 2] = s4.z; Ss[rr][c + 3] = s4.w;
        }
        __syncthreads();

        for (int kk = 0; kk < 32; ++kk) {
            float a[4], bv[4];
#pragma unroll
            for (int i = 0; i < 4; ++i) a[i] = Ts[tyt * 4 + i][kk];
#pragma unroll
            for (int j = 0; j < 4; ++j) bv[j] = Ss[txs * 4 + j][kk];
#pragma unroll
            for (int i = 0; i < 4; ++i)
#pragma unroll
                for (int j = 0; j < 4; ++j)
                    acc[i][j] += a[i] * bv[j];
        }
        __syncthreads();
    }
#pragma unroll
    for (int i = 0; i < 4; ++i) {
        const int t = tq * 32 + tyt * 4 + i;
#pragma unroll
        for (int j = 0; j < 4; ++j) {
            const int s = txs * 4 + j;
            Cm[((size_t)b * TDIM + t) * TDIM + s] = acc[i][j];
        }
    }
}

// ---------------------------------------------------------------------------
// K4 v3: tiled value recurrence (TB=32). Per block: 128 threads = one
// (b, 128-h chunk); thread j owns column h0+j end-to-end.
//   dense phase: pre[tt] += C[t0+tt][s]*hist[s][j] over all completed tiles —
//     32 independent register accumulators, static unroll, high ILP.
//   serial phase (scatter form): when vtr_u is produced, scatter
//     CdT[u][tt]*vtr_u into future pre[tt]. CdT is the 32x32 C diagonal
//     block, transposed + lower-triangle-zeroed so the scatter is a fully
//     static full-width unroll (no triangular control flow).
//   Serial dep chain per step = tanh + ~4 FMA (~30 cy), everything else
//   pipelines. hist is thread-column-private -> no barriers except around
//   the cooperative CdT staging (2 per tile).
// ---------------------------------------------------------------------------
__global__ __launch_bounds__(128) void k4_value(const float* __restrict__ I,
                                                const float* __restrict__ Cm,
                                                float* __restrict__ vals,
                                                float* __restrict__ vtr_g) {
    __shared__ float Cs[TDIM][TDIM];      // 64 KB, broadcast reads
    __shared__ float hist[96][128];       // 48 KB, column-private (s<96 only)
    __shared__ float CdT[32][32];         // 4 KB, staged per tile
    const int b = blockIdx.y;
    const int h0 = blockIdx.x * 128;
    const int j = threadIdx.x;
    const int h = h0 + j;

    // stage C[b] cooperatively: 16384 floats, coalesced float4
    {
        const float* Cb = &Cm[(size_t)b * TDIM * TDIM];
        float* Cf = &Cs[0][0];
#pragma unroll
        for (int u = 0; u < 32; ++u) {
            const int idx = (u * 128 + j) * 4;
            *(float4*)&Cf[idx] = *(const float4*)&Cb[idx];
        }
    }
    __syncthreads();

    const float* Ibase = I + (size_t)b * TDIM * (2 * HID) + HID + h;
    float* vals_base = vals + (size_t)b * TDIM * HID + h;
    float* vtr_base = vtr_g + (size_t)b * TDIM * HID + h;

    float vv = 0.f, vtr_c = 0.f;

    for (int tile = 0; tile < 4; ++tile) {
        const int t0 = tile * 32;

        // ---- stage CdT[u][tt] = (tt>u) ? Cs[t0+tt][t0+u] : 0  (1024 entries)
        {
            const int e0 = j * 8;
#pragma unroll
            for (int q = 0; q < 8; ++q) {
                const int e = e0 + q;
                const int u = e >> 5;
                const int tt = e & 31;
                CdT[u][tt] = (tt > u) ? Cs[t0 + tt][t0 + u] : 0.f;
            }
        }

        // ---- prefetch this tile's iv values (independent loads)
        float ivp[32];
#pragma unroll
        for (int u = 0; u < 32; ++u) ivp[u] = Ibase[(size_t)(t0 + u) * (2 * HID)];

        // ---- dense phase: contributions from all completed tiles
        float pre[32];
#pragma unroll
        for (int u = 0; u < 32; ++u) pre[u] = 0.f;
        for (int sc = 0; sc < t0; sc += 4) {
            const float hv0 = hist[sc + 0][j];
            const float hv1 = hist[sc + 1][j];
            const float hv2 = hist[sc + 2][j];
            const float hv3 = hist[sc + 3][j];
#pragma unroll
            for (int tt = 0; tt < 32; ++tt) {
                float4 c4 = *(const float4*)&Cs[t0 + tt][sc];   // broadcast
                pre[tt] += c4.x * hv0 + c4.y * hv1 + c4.z * hv2 + c4.w * hv3;
            }
        }
        __syncthreads();   // CdT visible to all threads

        // ---- serial phase: 32 steps, scatter-on-write
#pragma unroll
        for (int u = 0; u < 32; ++u) {
            const float ikv = pre[u];
            vv = ALPHA_F * vv + (1.f - ALPHA_F) * (ivp[u] + IKV_SCALE * ikv);
            const float val = tanhf(vv);
            vtr_c = DECAY_F * vtr_c + (1.f - DECAY_F) * val;
            vals_base[(size_t)(t0 + u) * HID] = val;
            vtr_base[(size_t)(t0 + u) * HID] = vtr_c;
            if (tile < 3) hist[t0 + u][j] = vtr_c;   // own column, no barrier
#pragma unroll
            for (int c = 0; c < 8; ++c) {
                float4 cd = *(const float4*)&CdT[u][c * 4];     // broadcast
                pre[c * 4 + 0] += cd.x * vtr_c;
                pre[c * 4 + 1] += cd.y * vtr_c;
                pre[c * 4 + 2] += cd.z * vtr_c;
                pre[c * 4 + 3] += cd.w * vtr_c;
            }
        }
        __syncthreads();   // all readers done before next tile restages CdT
    }
}

// ---------------------------------------------------------------------------
// K5: mem[b][i][j] = ETA * sum_t vtr[b][t][i] * ktr[b][t][j]
// ---------------------------------------------------------------------------
__global__ __launch_bounds__(256) void k5_mem(const float* __restrict__ vtr_g,
                                              const float* __restrict__ ktr_g,
                                              float* __restrict__ mem) {
    __shared__ float Vs[16][68];
    __shared__ float Ks[16][68];
    const int b = blockIdx.z;
    const int i0 = blockIdx.y * 64;
    const int j0 = blockIdx.x * 64;
    const int tid = threadIdx.x;
    const int tx = tid & 15;
    const int ty = tid >> 4;
    float acc[4][4] = {};

    for (int t0 = 0; t0 < TDIM; t0 += 16) {
        const int tt = tid >> 4;
        const int c4 = (tid & 15) * 4;
        *(float4*)&Vs[tt][c4] = *(const float4*)&vtr_g[((size_t)b * TDIM + t0 + tt) * HID + i0 + c4];
        *(float4*)&Ks[tt][c4] = *(const float4*)&ktr_g[((size_t)b * TDIM + t0 + tt) * HID + j0 + c4];
        __syncthreads();

        for (int k = 0; k < 16; ++k) {
            float4 a = *(const float4*)&Vs[k][ty * 4];
            float4 bv = *(const float4*)&Ks[k][tx * 4];
            acc[0][0] += a.x * bv.x; acc[0][1] += a.x * bv.y; acc[0][2] += a.x * bv.z; acc[0][3] += a.x * bv.w;
            acc[1][0] += a.y * bv.x; acc[1][1] += a.y * bv.y; acc[1][2] += a.y * bv.z; acc[1][3] += a.y * bv.w;
            acc[2][0] += a.z * bv.x; acc[2][1] += a.z * bv.y; acc[2][2] += a.z * bv.z; acc[2][3] += a.z * bv.w;
            acc[3][0] += a.w * bv.x; acc[3][1] += a.w * bv.y; acc[3][2] += a.w * bv.z; acc[3][3] += a.w * bv.w;
        }
        __syncthreads();
    }
#pragma unroll
    for (int i = 0; i < 4; ++i) {
        float4 o;
        o.x = ETA_F * acc[i][0];
        o.y = ETA_F * acc[i][1];
        o.z = ETA_F * acc[i][2];
        o.w = ETA_F * acc[i][3];
        *(float4*)&mem[((size_t)b * HID + i0 + ty * 4 + i) * HID + j0 + tx * 4] = o;
    }
}

// ---------------------------------------------------------------------------
extern "C" void kernel_launch(void* const* d_in, const int* in_sizes, int n_in,
                              void* d_out, int out_size, void* d_ws, size_t ws_size,
                              hipStream_t stream) {
    (void)in_sizes; (void)n_in; (void)out_size; (void)ws_size;
    const float* x = (const float*)d_in[0];   // (32,128,256)
    const float* W = (const float*)d_in[1];   // (1536,256)

    float* out = (float*)d_out;
    float* mem_out = out;                                        // 32*768*768
    float* keys_out = out + (size_t)BDIM * HID * HID;            // 32*128*768
    float* vals_out = keys_out + (size_t)BDIM * TDIM * HID;      // 32*128*768

    float* i_buf = (float*)d_ws;                                 // (B*T, 1536)
    float* ktr_g = i_buf + (size_t)BDIM * TDIM * 2 * HID;        // (B*T, 768)
    float* vtr_g = ktr_g + (size_t)BDIM * TDIM * HID;            // (B*T, 768)
    float* C_buf = vtr_g + (size_t)BDIM * TDIM * HID;            // (B, T, T)

    hipLaunchKernelGGL(k1_gemm, dim3(64, 24), dim3(256), 0, stream, x, W, i_buf);
    hipLaunchKernelGGL(k2_key, dim3(96), dim3(256), 0, stream, i_buf, keys_out, ktr_g);
    hipLaunchKernelGGL(k3_cmat, dim3(32, 4), dim3(256), 0, stream, keys_out, ktr_g, C_buf);
    hipLaunchKernelGGL(k4_value, dim3(6, 32), dim3(128), 0, stream, i_buf, C_buf, vals_out, vtr_g);
    hipLaunchKernelGGL(k5_mem, dim3(12, 12, 32), dim3(256), 0, stream, vtr_g, ktr_g, mem_out);
}

// Round 6
// 238.334 us; speedup vs baseline: 2.1401x; 1.5160x over previous
//
#include <hip/hip_runtime.h>
#include <math.h>

#define BDIM 32
#define TDIM 128
#define HID 768
#define INP 256

#define ALPHA_F 0.9512294245007140f
#define DECAY_F 0.9512294245007140f
#define ETA_F 0.1f
#define IKV_SCALE 0.02f

typedef __attribute__((ext_vector_type(8))) short bf16x8;
typedef __attribute__((ext_vector_type(4))) float f32x4_t;

__device__ inline unsigned short f2bf(float f) {
    unsigned int u = __builtin_bit_cast(unsigned int, f);
    u += 0x7fffu + ((u >> 16) & 1u);      // round-to-nearest-even
    return (unsigned short)(u >> 16);
}

__device__ inline bf16x8 pack2(float4 a, float4 b) {
    bf16x8 r;
    r[0] = (short)f2bf(a.x); r[1] = (short)f2bf(a.y);
    r[2] = (short)f2bf(a.z); r[3] = (short)f2bf(a.w);
    r[4] = (short)f2bf(b.x); r[5] = (short)f2bf(b.y);
    r[6] = (short)f2bf(b.z); r[7] = (short)f2bf(b.w);
    return r;
}

// ---------------------------------------------------------------------------
// K1 (MFMA): I[4096][1536] = X[4096][256] @ W[1536][256]^T, bf16 in / f32 out.
// 128x128 tile, BK=32, 4 waves (2x2, 64x64 each). fp32->bf16 on staging.
// LDS rows 64 B, XOR swizzle ((row&3)<<4) on both write and read sides.
// ---------------------------------------------------------------------------
__global__ __launch_bounds__(256) void k1_mfma(const float* __restrict__ X,
                                               const float* __restrict__ W,
                                               float* __restrict__ I) {
    __shared__ short As[128 * 32];
    __shared__ short Bs[128 * 32];
    const int tid = threadIdx.x;
    const int lane = tid & 63;
    const int wid = tid >> 6;
    const int wm = wid >> 1, wn = wid & 1;
    const int r0 = blockIdx.x * 128, n0 = blockIdx.y * 128;
    const int fr = lane & 15, q4 = lane >> 4;

    const int srow = tid >> 1;          // 0..127
    const int shalf = tid & 1;          // 16-float half
    const float* ax = &X[(size_t)(r0 + srow) * INP + shalf * 16];
    const float* bw = &W[(size_t)(n0 + srow) * INP + shalf * 16];
    const int swz = (srow & 3) << 4;
    char* asw = (char*)As + srow * 64;
    char* bsw = (char*)Bs + srow * 64;

    f32x4_t zz = {0.f, 0.f, 0.f, 0.f};
    f32x4_t acc[4][4];
#pragma unroll
    for (int m = 0; m < 4; ++m)
#pragma unroll
        for (int n = 0; n < 4; ++n) acc[m][n] = zz;

    float4 ra[4], rb[4];
#pragma unroll
    for (int q = 0; q < 4; ++q) {
        ra[q] = *(const float4*)(ax + q * 4);
        rb[q] = *(const float4*)(bw + q * 4);
    }

    for (int kt = 0; kt < 8; ++kt) {
        *(bf16x8*)(asw + (((shalf * 32) ^ swz)))      = pack2(ra[0], ra[1]);
        *(bf16x8*)(asw + (((shalf * 32 + 16) ^ swz))) = pack2(ra[2], ra[3]);
        *(bf16x8*)(bsw + (((shalf * 32) ^ swz)))      = pack2(rb[0], rb[1]);
        *(bf16x8*)(bsw + (((shalf * 32 + 16) ^ swz))) = pack2(rb[2], rb[3]);
        __syncthreads();
        if (kt < 7) {
#pragma unroll
            for (int q = 0; q < 4; ++q) {
                ra[q] = *(const float4*)(ax + (kt + 1) * 32 + q * 4);
                rb[q] = *(const float4*)(bw + (kt + 1) * 32 + q * 4);
            }
        }
        bf16x8 af[4], bfv[4];
#pragma unroll
        for (int m = 0; m < 4; ++m) {
            const int row = wm * 64 + m * 16 + fr;
            af[m] = *(const bf16x8*)((const char*)As + row * 64 + ((q4 * 16) ^ ((row & 3) << 4)));
        }
#pragma unroll
        for (int n = 0; n < 4; ++n) {
            const int row = wn * 64 + n * 16 + fr;
            bfv[n] = *(const bf16x8*)((const char*)Bs + row * 64 + ((q4 * 16) ^ ((row & 3) << 4)));
        }
#pragma unroll
        for (int m = 0; m < 4; ++m)
#pragma unroll
            for (int n = 0; n < 4; ++n)
                acc[m][n] = __builtin_amdgcn_mfma_f32_16x16x32_bf16(af[m], bfv[n], acc[m][n], 0, 0, 0);
        __syncthreads();
    }
#pragma unroll
    for (int m = 0; m < 4; ++m)
#pragma unroll
        for (int n = 0; n < 4; ++n)
#pragma unroll
            for (int r = 0; r < 4; ++r)
                I[(size_t)(r0 + wm * 64 + m * 16 + q4 * 4 + r) * (2 * HID)
                  + n0 + wn * 64 + n * 16 + fr] = acc[m][n][r];
}

// ---------------------------------------------------------------------------
// K2: key recurrence; emits keys fp32 (output), keys/ktr bf16 [t][h] (for k3),
//     ktrT bf16 [h][t] (for k5).
// ---------------------------------------------------------------------------
__global__ __launch_bounds__(256) void k2_key(const float* __restrict__ I,
                                              float* __restrict__ keys,
                                              unsigned short* __restrict__ keys_bf,
                                              unsigned short* __restrict__ ktr_bf,
                                              unsigned short* __restrict__ ktrT) {
    const int gid = blockIdx.x * 256 + threadIdx.x;
    const int b = gid / HID;
    const int h = gid % HID;
    const float* Ib = I + (size_t)b * TDIM * (2 * HID) + h;
    float* kb = keys + (size_t)b * TDIM * HID + h;
    unsigned short* kbf = keys_bf + (size_t)b * TDIM * HID + h;
    unsigned short* tbf = ktr_bf + (size_t)b * TDIM * HID + h;
    unsigned short* ktT = ktrT + ((size_t)b * HID + h) * TDIM;
    float kv = 0.f, kt = 0.f;
    for (int t0 = 0; t0 < TDIM; t0 += 8) {
        float ik[8];
#pragma unroll
        for (int q = 0; q < 8; ++q) ik[q] = Ib[(size_t)(t0 + q) * (2 * HID)];
        bf16x8 kt8;
#pragma unroll
        for (int q = 0; q < 8; ++q) {
            kv = ALPHA_F * kv + (1.f - ALPHA_F) * ik[q];
            float ko = tanhf(kv);
            kb[(size_t)(t0 + q) * HID] = ko;
            kbf[(size_t)(t0 + q) * HID] = f2bf(ko);
            kt = DECAY_F * kt + (1.f - DECAY_F) * ko;
            tbf[(size_t)(t0 + q) * HID] = f2bf(kt);
            kt8[q] = (short)f2bf(kt);
        }
        *(bf16x8*)(ktT + t0) = kt8;
    }
}

// ---------------------------------------------------------------------------
// K3 (MFMA): C[b][t][s] = sum_h keys[t][h]*ktr[s][h]. Per block: 64(t)x128(s),
// BK=32 over K=768, bf16 staged from k2's copies, fp32 out.
// ---------------------------------------------------------------------------
__global__ __launch_bounds__(256) void k3_mfma(const unsigned short* __restrict__ keys_bf,
                                               const unsigned short* __restrict__ ktr_bf,
                                               float* __restrict__ Cm) {
    __shared__ short Ak[64 * 32];
    __shared__ short Bk[128 * 32];
    const int tq = blockIdx.x;          // t half
    const int b = blockIdx.y;
    const int tid = threadIdx.x;
    const int lane = tid & 63;
    const int wid = tid >> 6;
    const int wm = wid >> 1, wn = wid & 1;
    const int fr = lane & 15, q4 = lane >> 4;

    const int arow = tid >> 2, aq = tid & 3;       // keys: 64 rows x 1 short8
    const int brow = tid >> 1, bh = tid & 1;       // ktr: 128 rows x 2 short8
    const unsigned short* gk = keys_bf + ((size_t)b * TDIM + tq * 64 + arow) * HID + aq * 8;
    const unsigned short* gt = ktr_bf + ((size_t)b * TDIM + brow) * HID + bh * 16;
    char* akw = (char*)Ak + arow * 64;
    char* bkw = (char*)Bk + brow * 64;
    const int aswz = (arow & 3) << 4, bswz = (brow & 3) << 4;

    f32x4_t zz = {0.f, 0.f, 0.f, 0.f};
    f32x4_t acc[2][4];
#pragma unroll
    for (int m = 0; m < 2; ++m)
#pragma unroll
        for (int n = 0; n < 4; ++n) acc[m][n] = zz;

    bf16x8 pk = *(const bf16x8*)gk;
    bf16x8 pt0 = *(const bf16x8*)gt;
    bf16x8 pt1 = *(const bf16x8*)(gt + 8);

    for (int kt = 0; kt < 24; ++kt) {
        *(bf16x8*)(akw + ((aq * 16) ^ aswz)) = pk;
        *(bf16x8*)(bkw + ((bh * 32) ^ bswz)) = pt0;
        *(bf16x8*)(bkw + ((bh * 32 + 16) ^ bswz)) = pt1;
        __syncthreads();
        if (kt < 23) {
            pk = *(const bf16x8*)(gk + (kt + 1) * 32);
            pt0 = *(const bf16x8*)(gt + (kt + 1) * 32);
            pt1 = *(const bf16x8*)(gt + (kt + 1) * 32 + 8);
        }
        bf16x8 af[2], bfv[4];
#pragma unroll
        for (int m = 0; m < 2; ++m) {
            const int row = wm * 32 + m * 16 + fr;
            af[m] = *(const bf16x8*)((const char*)Ak + row * 64 + ((q4 * 16) ^ ((row & 3) << 4)));
        }
#pragma unroll
        for (int n = 0; n < 4; ++n) {
            const int row = wn * 64 + n * 16 + fr;
            bfv[n] = *(const bf16x8*)((const char*)Bk + row * 64 + ((q4 * 16) ^ ((row & 3) << 4)));
        }
#pragma unroll
        for (int m = 0; m < 2; ++m)
#pragma unroll
            for (int n = 0; n < 4; ++n)
                acc[m][n] = __builtin_amdgcn_mfma_f32_16x16x32_bf16(af[m], bfv[n], acc[m][n], 0, 0, 0);
        __syncthreads();
    }
#pragma unroll
    for (int m = 0; m < 2; ++m)
#pragma unroll
        for (int n = 0; n < 4; ++n)
#pragma unroll
            for (int r = 0; r < 4; ++r) {
                const int t = tq * 64 + wm * 32 + m * 16 + q4 * 4 + r;
                const int s = wn * 64 + n * 16 + fr;
                Cm[((size_t)b * TDIM + t) * TDIM + s] = acc[m][n][r];
            }
}

// ---------------------------------------------------------------------------
// K4: tiled value recurrence (unchanged structure); emits vals fp32 (output)
//     and vtrT bf16 [h][t] (for k5).
// ---------------------------------------------------------------------------
__global__ __launch_bounds__(128) void k4_value(const float* __restrict__ I,
                                                const float* __restrict__ Cm,
                                                float* __restrict__ vals,
                                                unsigned short* __restrict__ vtrT) {
    __shared__ float Cs[TDIM][TDIM];      // 64 KB
    __shared__ float hist[96][128];       // 48 KB, column-private
    __shared__ float CdT[32][32];         // 4 KB
    const int b = blockIdx.y;
    const int h0 = blockIdx.x * 128;
    const int j = threadIdx.x;
    const int h = h0 + j;

    {
        const float* Cb = &Cm[(size_t)b * TDIM * TDIM];
        float* Cf = &Cs[0][0];
#pragma unroll
        for (int u = 0; u < 32; ++u) {
            const int idx = (u * 128 + j) * 4;
            *(float4*)&Cf[idx] = *(const float4*)&Cb[idx];
        }
    }
    __syncthreads();

    const float* Ibase = I + (size_t)b * TDIM * (2 * HID) + HID + h;
    float* vals_base = vals + (size_t)b * TDIM * HID + h;
    unsigned short* vT = vtrT + ((size_t)b * HID + h) * TDIM;

    float vv = 0.f, vtr_c = 0.f;

    for (int tile = 0; tile < 4; ++tile) {
        const int t0 = tile * 32;

        {
            const int e0 = j * 8;
#pragma unroll
            for (int q = 0; q < 8; ++q) {
                const int e = e0 + q;
                const int u = e >> 5;
                const int tt = e & 31;
                CdT[u][tt] = (tt > u) ? Cs[t0 + tt][t0 + u] : 0.f;
            }
        }

        float ivp[32];
#pragma unroll
        for (int u = 0; u < 32; ++u) ivp[u] = Ibase[(size_t)(t0 + u) * (2 * HID)];

        float pre[32];
#pragma unroll
        for (int u = 0; u < 32; ++u) pre[u] = 0.f;
        for (int sc = 0; sc < t0; sc += 4) {
            const float hv0 = hist[sc + 0][j];
            const float hv1 = hist[sc + 1][j];
            const float hv2 = hist[sc + 2][j];
            const float hv3 = hist[sc + 3][j];
#pragma unroll
            for (int tt = 0; tt < 32; ++tt) {
                float4 c4 = *(const float4*)&Cs[t0 + tt][sc];
                pre[tt] += c4.x * hv0 + c4.y * hv1 + c4.z * hv2 + c4.w * hv3;
            }
        }
        __syncthreads();

        unsigned short vb[32];
#pragma unroll
        for (int u = 0; u < 32; ++u) {
            const float ikv = pre[u];
            vv = ALPHA_F * vv + (1.f - ALPHA_F) * (ivp[u] + IKV_SCALE * ikv);
            const float val = tanhf(vv);
            vtr_c = DECAY_F * vtr_c + (1.f - DECAY_F) * val;
            vals_base[(size_t)(t0 + u) * HID] = val;
            vb[u] = f2bf(vtr_c);
            if (tile < 3) hist[t0 + u][j] = vtr_c;
#pragma unroll
            for (int c = 0; c < 8; ++c) {
                float4 cd = *(const float4*)&CdT[u][c * 4];
                pre[c * 4 + 0] += cd.x * vtr_c;
                pre[c * 4 + 1] += cd.y * vtr_c;
                pre[c * 4 + 2] += cd.z * vtr_c;
                pre[c * 4 + 3] += cd.w * vtr_c;
            }
        }
#pragma unroll
        for (int q8 = 0; q8 < 4; ++q8) {
            bf16x8 p;
#pragma unroll
            for (int c = 0; c < 8; ++c) p[c] = (short)vb[q8 * 8 + c];
            *(bf16x8*)(vT + t0 + q8 * 8) = p;
        }
        __syncthreads();
    }
}

// ---------------------------------------------------------------------------
// K5 (MFMA): mem[b][i][j] = ETA * sum_t vtrT[i][t] * ktrT[j][t].
// 128x128 tile, 4 waves, fragments straight from global (L2-resident), no LDS.
// ---------------------------------------------------------------------------
__global__ __launch_bounds__(256) void k5_mfma(const unsigned short* __restrict__ vtrT,
                                               const unsigned short* __restrict__ ktrT,
                                               float* __restrict__ mem) {
    const int b = blockIdx.z;
    const int i0 = blockIdx.y * 128;
    const int j0 = blockIdx.x * 128;
    const int tid = threadIdx.x;
    const int lane = tid & 63;
    const int wid = tid >> 6;
    const int wm = wid >> 1, wn = wid & 1;
    const int fr = lane & 15, q4 = lane >> 4;

    const unsigned short* Ab = vtrT + ((size_t)b * HID + i0 + wm * 64) * TDIM;
    const unsigned short* Bb = ktrT + ((size_t)b * HID + j0 + wn * 64) * TDIM;

    f32x4_t zz = {0.f, 0.f, 0.f, 0.f};
    f32x4_t acc[4][4];
#pragma unroll
    for (int m = 0; m < 4; ++m)
#pragma unroll
        for (int n = 0; n < 4; ++n) acc[m][n] = zz;

#pragma unroll
    for (int kt = 0; kt < 4; ++kt) {
        bf16x8 af[4], bfv[4];
#pragma unroll
        for (int m = 0; m < 4; ++m)
            af[m] = *(const bf16x8*)(Ab + (size_t)(m * 16 + fr) * TDIM + kt * 32 + q4 * 8);
#pragma unroll
        for (int n = 0; n < 4; ++n)
            bfv[n] = *(const bf16x8*)(Bb + (size_t)(n * 16 + fr) * TDIM + kt * 32 + q4 * 8);
#pragma unroll
        for (int m = 0; m < 4; ++m)
#pragma unroll
            for (int n = 0; n < 4; ++n)
                acc[m][n] = __builtin_amdgcn_mfma_f32_16x16x32_bf16(af[m], bfv[n], acc[m][n], 0, 0, 0);
    }
#pragma unroll
    for (int m = 0; m < 4; ++m)
#pragma unroll
        for (int n = 0; n < 4; ++n)
#pragma unroll
            for (int r = 0; r < 4; ++r)
                mem[((size_t)b * HID + i0 + wm * 64 + m * 16 + q4 * 4 + r) * HID
                    + j0 + wn * 64 + n * 16 + fr] = ETA_F * acc[m][n][r];
}

// ---------------------------------------------------------------------------
extern "C" void kernel_launch(void* const* d_in, const int* in_sizes, int n_in,
                              void* d_out, int out_size, void* d_ws, size_t ws_size,
                              hipStream_t stream) {
    (void)in_sizes; (void)n_in; (void)out_size; (void)ws_size;
    const float* x = (const float*)d_in[0];   // (32,128,256)
    const float* W = (const float*)d_in[1];   // (1536,256)

    float* out = (float*)d_out;
    float* mem_out = out;                                        // 32*768*768
    float* keys_out = out + (size_t)BDIM * HID * HID;            // 32*128*768
    float* vals_out = keys_out + (size_t)BDIM * TDIM * HID;      // 32*128*768

    // workspace: i_buf 25.2MB | C 2.1MB | 4x bf16 buffers 6.29MB = 52.4MB
    float* i_buf = (float*)d_ws;                                 // (B*T, 1536) f32
    float* C_buf = i_buf + (size_t)BDIM * TDIM * 2 * HID;        // (B, T, T) f32
    unsigned short* bf_base = (unsigned short*)(C_buf + (size_t)BDIM * TDIM * TDIM);
    unsigned short* keys_bf = bf_base;                           // (B*T, H) bf16
    unsigned short* ktr_bf = keys_bf + (size_t)BDIM * TDIM * HID;
    unsigned short* ktrT = ktr_bf + (size_t)BDIM * TDIM * HID;   // (B, H, T) bf16
    unsigned short* vtrT = ktrT + (size_t)BDIM * HID * TDIM;     // (B, H, T) bf16

    hipLaunchKernelGGL(k1_mfma, dim3(32, 12), dim3(256), 0, stream, x, W, i_buf);
    hipLaunchKernelGGL(k2_key, dim3(96), dim3(256), 0, stream, i_buf, keys_out, keys_bf, ktr_bf, ktrT);
    hipLaunchKernelGGL(k3_mfma, dim3(2, 32), dim3(256), 0, stream, keys_bf, ktr_bf, C_buf);
    hipLaunchKernelGGL(k4_value, dim3(6, 32), dim3(128), 0, stream, i_buf, C_buf, vals_out, vtrT);
    hipLaunchKernelGGL(k5_mfma, dim3(6, 6, 32), dim3(256), 0, stream, vtrT, ktrT, mem_out);
}

// Round 9
// 195.485 us; speedup vs baseline: 2.6092x; 1.2192x over previous
//
#include <hip/hip_runtime.h>
#include <math.h>

#define BDIM 32
#define TDIM 128
#define HID 768
#define INP 256

#define ALPHA_F 0.9512294245007140f
#define DECAY_F 0.9512294245007140f
#define ETA_F 0.1f
#define IKV_SCALE 0.02f

typedef __attribute__((ext_vector_type(8))) short bf16x8;
typedef __attribute__((ext_vector_type(4))) float f32x4_t;

__device__ inline unsigned short f2bf(float f) {
    unsigned int u = __builtin_bit_cast(unsigned int, f);
    u += 0x7fffu + ((u >> 16) & 1u);      // round-to-nearest-even
    return (unsigned short)(u >> 16);
}

__device__ inline float bf2f(unsigned short us) {
    unsigned int ui = ((unsigned int)us) << 16;
    return __builtin_bit_cast(float, ui);
}

__device__ inline bf16x8 pack2(float4 a, float4 b) {
    bf16x8 r;
    r[0] = (short)f2bf(a.x); r[1] = (short)f2bf(a.y);
    r[2] = (short)f2bf(a.z); r[3] = (short)f2bf(a.w);
    r[4] = (short)f2bf(b.x); r[5] = (short)f2bf(b.y);
    r[6] = (short)f2bf(b.z); r[7] = (short)f2bf(b.w);
    return r;
}

// ---------------------------------------------------------------------------
// K1 (fused GEMM + key recurrence).
// GEMM: 128x128 tile of I = X @ W^T (bf16 MFMA, fp32 acc). M-tile = one batch
// (rows b*128..b*128+127 = all t of batch b).
//   key blocks  (n0 < 768): transpose acc through LDS (overlaying As/Bs),
//     then threads 0..127 run the kv/ktr recurrence over t for their column,
//     emitting keys (f32 out), keys_bf, ktr_bf [t][h], ktrT [h][t].
//   value blocks (n0>=768): write slim i_buf (B*T, 768).
// ---------------------------------------------------------------------------
__global__ __launch_bounds__(256) void k1_fused(const float* __restrict__ X,
                                                const float* __restrict__ W,
                                                float* __restrict__ i_buf,
                                                float* __restrict__ keys,
                                                unsigned short* __restrict__ keys_bf,
                                                unsigned short* __restrict__ ktr_bf,
                                                unsigned short* __restrict__ ktrT) {
    __shared__ __align__(16) float Ts[128 * 132];   // 67.6 KB; As/Bs overlay
    short* As = (short*)Ts;                          // 128x32 bf16, 64B rows
    short* Bs = As + 128 * 32;
    const int tid = threadIdx.x;
    const int lane = tid & 63;
    const int wid = tid >> 6;
    const int wm = wid >> 1, wn = wid & 1;
    const int b = blockIdx.x;
    const int r0 = b * 128, n0 = blockIdx.y * 128;
    const int fr = lane & 15, q4 = lane >> 4;

    const int srow = tid >> 1;          // 0..127
    const int shalf = tid & 1;          // 16-float half
    const float* ax = &X[(size_t)(r0 + srow) * INP + shalf * 16];
    const float* bw = &W[(size_t)(n0 + srow) * INP + shalf * 16];
    const int swz = (srow & 3) << 4;
    char* asw = (char*)As + srow * 64;
    char* bsw = (char*)Bs + srow * 64;

    f32x4_t zz = {0.f, 0.f, 0.f, 0.f};
    f32x4_t acc[4][4];
#pragma unroll
    for (int m = 0; m < 4; ++m)
#pragma unroll
        for (int n = 0; n < 4; ++n) acc[m][n] = zz;

    float4 ra[4], rb[4];
#pragma unroll
    for (int q = 0; q < 4; ++q) {
        ra[q] = *(const float4*)(ax + q * 4);
        rb[q] = *(const float4*)(bw + q * 4);
    }

    for (int kt = 0; kt < 8; ++kt) {
        *(bf16x8*)(asw + (((shalf * 32) ^ swz)))      = pack2(ra[0], ra[1]);
        *(bf16x8*)(asw + (((shalf * 32 + 16) ^ swz))) = pack2(ra[2], ra[3]);
        *(bf16x8*)(bsw + (((shalf * 32) ^ swz)))      = pack2(rb[0], rb[1]);
        *(bf16x8*)(bsw + (((shalf * 32 + 16) ^ swz))) = pack2(rb[2], rb[3]);
        __syncthreads();
        if (kt < 7) {
#pragma unroll
            for (int q = 0; q < 4; ++q) {
                ra[q] = *(const float4*)(ax + (kt + 1) * 32 + q * 4);
                rb[q] = *(const float4*)(bw + (kt + 1) * 32 + q * 4);
            }
        }
        bf16x8 af[4], bfv[4];
#pragma unroll
        for (int m = 0; m < 4; ++m) {
            const int row = wm * 64 + m * 16 + fr;
            af[m] = *(const bf16x8*)((const char*)As + row * 64 + ((q4 * 16) ^ ((row & 3) << 4)));
        }
#pragma unroll
        for (int n = 0; n < 4; ++n) {
            const int row = wn * 64 + n * 16 + fr;
            bfv[n] = *(const bf16x8*)((const char*)Bs + row * 64 + ((q4 * 16) ^ ((row & 3) << 4)));
        }
#pragma unroll
        for (int m = 0; m < 4; ++m)
#pragma unroll
            for (int n = 0; n < 4; ++n)
                acc[m][n] = __builtin_amdgcn_mfma_f32_16x16x32_bf16(af[m], bfv[n], acc[m][n], 0, 0, 0);
        __syncthreads();
    }

    if (n0 < HID) {
        // ---- key block: transpose acc -> Ts, then recurrence per column
#pragma unroll
        for (int m = 0; m < 4; ++m)
#pragma unroll
            for (int n = 0; n < 4; ++n)
#pragma unroll
                for (int r = 0; r < 4; ++r)
                    Ts[(wm * 64 + m * 16 + q4 * 4 + r) * 132 + wn * 64 + n * 16 + fr] = acc[m][n][r];
        __syncthreads();
        if (tid < 128) {
            const int h = n0 + tid;
            float* kb = keys + (size_t)r0 * HID + h;
            unsigned short* kbf = keys_bf + (size_t)r0 * HID + h;
            unsigned short* tbf = ktr_bf + (size_t)r0 * HID + h;
            unsigned short* ktT = ktrT + ((size_t)b * HID + h) * TDIM;
            float kv = 0.f, kt = 0.f;
            for (int t0 = 0; t0 < TDIM; t0 += 8) {
                bf16x8 kp;
#pragma unroll
                for (int q = 0; q < 8; ++q) {
                    const int t = t0 + q;
                    const float ik = Ts[t * 132 + tid];
                    kv = ALPHA_F * kv + (1.f - ALPHA_F) * ik;
                    const float ko = tanhf(kv);
                    kb[(size_t)t * HID] = ko;
                    kbf[(size_t)t * HID] = f2bf(ko);
                    kt = DECAY_F * kt + (1.f - DECAY_F) * ko;
                    tbf[(size_t)t * HID] = f2bf(kt);
                    kp[q] = (short)f2bf(kt);
                }
                *(bf16x8*)(ktT + t0) = kp;
            }
        }
    } else {
        // ---- value block: write slim i_buf
        const int c0 = n0 - HID;
#pragma unroll
        for (int m = 0; m < 4; ++m)
#pragma unroll
            for (int n = 0; n < 4; ++n)
#pragma unroll
                for (int r = 0; r < 4; ++r)
                    i_buf[(size_t)(r0 + wm * 64 + m * 16 + q4 * 4 + r) * HID
                          + c0 + wn * 64 + n * 16 + fr] = acc[m][n][r];
    }
}

// ---------------------------------------------------------------------------
// K3 (MFMA): C[b][t][s] = sum_h keys[t][h]*ktr[s][h]; bf16 OUT (for k4).
// ---------------------------------------------------------------------------
__global__ __launch_bounds__(256) void k3_mfma(const unsigned short* __restrict__ keys_bf,
                                               const unsigned short* __restrict__ ktr_bf,
                                               unsigned short* __restrict__ Cbf) {
    __shared__ short Ak[64 * 32];
    __shared__ short Bk[128 * 32];
    const int tq = blockIdx.x;          // t half
    const int b = blockIdx.y;
    const int tid = threadIdx.x;
    const int lane = tid & 63;
    const int wid = tid >> 6;
    const int wm = wid >> 1, wn = wid & 1;
    const int fr = lane & 15, q4 = lane >> 4;

    const int arow = tid >> 2, aq = tid & 3;
    const int brow = tid >> 1, bh = tid & 1;
    const unsigned short* gk = keys_bf + ((size_t)b * TDIM + tq * 64 + arow) * HID + aq * 8;
    const unsigned short* gt = ktr_bf + ((size_t)b * TDIM + brow) * HID + bh * 16;
    char* akw = (char*)Ak + arow * 64;
    char* bkw = (char*)Bk + brow * 64;
    const int aswz = (arow & 3) << 4, bswz = (brow & 3) << 4;

    f32x4_t zz = {0.f, 0.f, 0.f, 0.f};
    f32x4_t acc[2][4];
#pragma unroll
    for (int m = 0; m < 2; ++m)
#pragma unroll
        for (int n = 0; n < 4; ++n) acc[m][n] = zz;

    bf16x8 pk = *(const bf16x8*)gk;
    bf16x8 pt0 = *(const bf16x8*)gt;
    bf16x8 pt1 = *(const bf16x8*)(gt + 8);

    for (int kt = 0; kt < 24; ++kt) {
        *(bf16x8*)(akw + ((aq * 16) ^ aswz)) = pk;
        *(bf16x8*)(bkw + ((bh * 32) ^ bswz)) = pt0;
        *(bf16x8*)(bkw + ((bh * 32 + 16) ^ bswz)) = pt1;
        __syncthreads();
        if (kt < 23) {
            pk = *(const bf16x8*)(gk + (kt + 1) * 32);
            pt0 = *(const bf16x8*)(gt + (kt + 1) * 32);
            pt1 = *(const bf16x8*)(gt + (kt + 1) * 32 + 8);
        }
        bf16x8 af[2], bfv[4];
#pragma unroll
        for (int m = 0; m < 2; ++m) {
            const int row = wm * 32 + m * 16 + fr;
            af[m] = *(const bf16x8*)((const char*)Ak + row * 64 + ((q4 * 16) ^ ((row & 3) << 4)));
        }
#pragma unroll
        for (int n = 0; n < 4; ++n) {
            const int row = wn * 64 + n * 16 + fr;
            bfv[n] = *(const bf16x8*)((const char*)Bk + row * 64 + ((q4 * 16) ^ ((row & 3) << 4)));
        }
#pragma unroll
        for (int m = 0; m < 2; ++m)
#pragma unroll
            for (int n = 0; n < 4; ++n)
                acc[m][n] = __builtin_amdgcn_mfma_f32_16x16x32_bf16(af[m], bfv[n], acc[m][n], 0, 0, 0);
        __syncthreads();
    }
#pragma unroll
    for (int m = 0; m < 2; ++m)
#pragma unroll
        for (int n = 0; n < 4; ++n)
#pragma unroll
            for (int r = 0; r < 4; ++r) {
                const int t = tq * 64 + wm * 32 + m * 16 + q4 * 4 + r;
                const int s = wn * 64 + n * 16 + fr;
                Cbf[((size_t)b * TDIM + t) * TDIM + s] = f2bf(acc[m][n][r]);
            }
}

// ---------------------------------------------------------------------------
// K4 v4: tiled value recurrence, dense phase on MFMA.
//   Block = 64 threads (1 wave) = one (b, 64-wide h chunk); grid 12 x 32.
//   LDS ~61 KB -> 2 blocks/CU, all 256 CUs busy.
//   Per tile: dense pre[tt] = C[t0+tt][s<t0] @ vtr-hist  via 16x16x32 bf16
//   MFMA (A = Cs bf16 [t][s], B = histb bf16 [h][s]); D redistributed through
//   padded pre_s so thread j owns its column. Serial 32-step scatter with
//   fp32 CdT (lower-tri-zeroed C diagonal block) as before.
// ---------------------------------------------------------------------------
__global__ __launch_bounds__(64) void k4_value(const float* __restrict__ IV,
                                               const unsigned short* __restrict__ Cbf,
                                               float* __restrict__ vals,
                                               unsigned short* __restrict__ vtrT) {
    __shared__ __align__(16) unsigned short Cs[128 * 136];    // 34.8 KB, 272B rows
    __shared__ __align__(16) unsigned short histb[64 * 104];  // 13.3 KB, 208B rows
    __shared__ float CdT[32 * 32];                            // 4 KB
    __shared__ float pre_s[32 * 68];                          // 8.7 KB
    const int b = blockIdx.y;
    const int h0 = blockIdx.x * 64;
    const int j = threadIdx.x;          // 0..63
    const int fr = j & 15, q4 = j >> 4;

    // stage C[b] (bf16): rows j and j+64
    {
        const unsigned short* Cb = Cbf + (size_t)b * TDIM * TDIM;
#pragma unroll
        for (int rr = 0; rr < 2; ++rr) {
            const int r = j + rr * 64;
#pragma unroll
            for (int s8 = 0; s8 < 16; ++s8)
                *(bf16x8*)((char*)Cs + r * 272 + s8 * 16) =
                    *(const bf16x8*)(Cb + r * TDIM + s8 * 8);
        }
    }
    __syncthreads();

    const float* Ibase = IV + (size_t)b * TDIM * HID + h0 + j;
    float* vals_base = vals + (size_t)b * TDIM * HID + h0 + j;
    unsigned short* vT = vtrT + ((size_t)b * HID + h0 + j) * TDIM;

    float vv = 0.f, vtr_c = 0.f;
    f32x4_t zz = {0.f, 0.f, 0.f, 0.f};

    for (int tile = 0; tile < 4; ++tile) {
        const int t0 = tile * 32;

        // ---- stage CdT[u][tt] = (tt>u) ? C[t0+tt][t0+u] : 0  (fp32)
#pragma unroll
        for (int q = 0; q < 16; ++q) {
            const int e = j * 16 + q;
            const int u = e >> 5, tt = e & 31;
            float v = 0.f;
            if (tt > u)
                v = bf2f(*(const unsigned short*)((const char*)Cs + (t0 + tt) * 272 + (t0 + u) * 2));
            CdT[u * 32 + tt] = v;
        }

        // ---- prefetch iv (independent global loads)
        float ivp[32];
#pragma unroll
        for (int u = 0; u < 32; ++u) ivp[u] = Ibase[(size_t)(t0 + u) * HID];

        // ---- dense phase via MFMA: pre_s[tt][h] = sum_{s<t0} C[t0+tt][s]*hist[h][s]
        if (tile > 0) {
            f32x4_t accd[2][4];
#pragma unroll
            for (int mt = 0; mt < 2; ++mt)
#pragma unroll
                for (int nt = 0; nt < 4; ++nt) accd[mt][nt] = zz;
            for (int kc = 0; kc < tile; ++kc) {
                bf16x8 afr[2], bfr[4];
#pragma unroll
                for (int mt = 0; mt < 2; ++mt)
                    afr[mt] = *(const bf16x8*)((const char*)Cs
                              + (size_t)(t0 + mt * 16 + fr) * 272 + kc * 64 + q4 * 16);
#pragma unroll
                for (int nt = 0; nt < 4; ++nt)
                    bfr[nt] = *(const bf16x8*)((const char*)histb
                              + (size_t)(nt * 16 + fr) * 208 + kc * 64 + q4 * 16);
#pragma unroll
                for (int mt = 0; mt < 2; ++mt)
#pragma unroll
                    for (int nt = 0; nt < 4; ++nt)
                        accd[mt][nt] = __builtin_amdgcn_mfma_f32_16x16x32_bf16(afr[mt], bfr[nt], accd[mt][nt], 0, 0, 0);
            }
#pragma unroll
            for (int mt = 0; mt < 2; ++mt)
#pragma unroll
                for (int nt = 0; nt < 4; ++nt)
#pragma unroll
                    for (int r = 0; r < 4; ++r)
                        pre_s[(mt * 16 + q4 * 4 + r) * 68 + nt * 16 + fr] = accd[mt][nt][r];
        }
        __syncthreads();   // CdT + pre_s visible

        float pre[32];
        if (tile > 0) {
#pragma unroll
            for (int tt = 0; tt < 32; ++tt) pre[tt] = pre_s[tt * 68 + j];
        } else {
#pragma unroll
            for (int tt = 0; tt < 32; ++tt) pre[tt] = 0.f;
        }

        // ---- serial phase: 32 steps, scatter-on-write
        unsigned short vb[32];
#pragma unroll
        for (int u = 0; u < 32; ++u) {
            vv = ALPHA_F * vv + (1.f - ALPHA_F) * (ivp[u] + IKV_SCALE * pre[u]);
            const float val = tanhf(vv);
            vtr_c = DECAY_F * vtr_c + (1.f - DECAY_F) * val;
            vals_base[(size_t)(t0 + u) * HID] = val;
            const unsigned short vbf = f2bf(vtr_c);
            vb[u] = vbf;
            if (tile < 3) histb[j * 104 + t0 + u] = vbf;   // own row, no race
#pragma unroll
            for (int c = 0; c < 8; ++c) {
                float4 cd = *(const float4*)&CdT[u * 32 + c * 4];   // broadcast
                pre[c * 4 + 0] += cd.x * vtr_c;
                pre[c * 4 + 1] += cd.y * vtr_c;
                pre[c * 4 + 2] += cd.z * vtr_c;
                pre[c * 4 + 3] += cd.w * vtr_c;
            }
        }
#pragma unroll
        for (int q8 = 0; q8 < 4; ++q8) {
            bf16x8 p;
#pragma unroll
            for (int c = 0; c < 8; ++c) p[c] = (short)vb[q8 * 8 + c];
            *(bf16x8*)(vT + t0 + q8 * 8) = p;
        }
        __syncthreads();   // hist/pre_s/CdT safe to rewrite next tile
    }
}

// ---------------------------------------------------------------------------
// K5 (MFMA): mem[b][i][j] = ETA * sum_t vtrT[i][t] * ktrT[j][t]. No LDS.
// ---------------------------------------------------------------------------
__global__ __launch_bounds__(256) void k5_mfma(const unsigned short* __restrict__ vtrT,
                                               const unsigned short* __restrict__ ktrT,
                                               float* __restrict__ mem) {
    const int b = blockIdx.z;
    const int i0 = blockIdx.y * 128;
    const int j0 = blockIdx.x * 128;
    const int tid = threadIdx.x;
    const int lane = tid & 63;
    const int wid = tid >> 6;
    const int wm = wid >> 1, wn = wid & 1;
    const int fr = lane & 15, q4 = lane >> 4;

    const unsigned short* Ab = vtrT + ((size_t)b * HID + i0 + wm * 64) * TDIM;
    const unsigned short* Bb = ktrT + ((size_t)b * HID + j0 + wn * 64) * TDIM;

    f32x4_t zz = {0.f, 0.f, 0.f, 0.f};
    f32x4_t acc[4][4];
#pragma unroll
    for (int m = 0; m < 4; ++m)
#pragma unroll
        for (int n = 0; n < 4; ++n) acc[m][n] = zz;

#pragma unroll
    for (int kt = 0; kt < 4; ++kt) {
        bf16x8 af[4], bfv[4];
#pragma unroll
        for (int m = 0; m < 4; ++m)
            af[m] = *(const bf16x8*)(Ab + (size_t)(m * 16 + fr) * TDIM + kt * 32 + q4 * 8);
#pragma unroll
        for (int n = 0; n < 4; ++n)
            bfv[n] = *(const bf16x8*)(Bb + (size_t)(n * 16 + fr) * TDIM + kt * 32 + q4 * 8);
#pragma unroll
        for (int m = 0; m < 4; ++m)
#pragma unroll
            for (int n = 0; n < 4; ++n)
                acc[m][n] = __builtin_amdgcn_mfma_f32_16x16x32_bf16(af[m], bfv[n], acc[m][n], 0, 0, 0);
    }
#pragma unroll
    for (int m = 0; m < 4; ++m)
#pragma unroll
        for (int n = 0; n < 4; ++n)
#pragma unroll
            for (int r = 0; r < 4; ++r)
                mem[((size_t)b * HID + i0 + wm * 64 + m * 16 + q4 * 4 + r) * HID
                    + j0 + wn * 64 + n * 16 + fr] = ETA_F * acc[m][n][r];
}

// ---------------------------------------------------------------------------
extern "C" void kernel_launch(void* const* d_in, const int* in_sizes, int n_in,
                              void* d_out, int out_size, void* d_ws, size_t ws_size,
                              hipStream_t stream) {
    (void)in_sizes; (void)n_in; (void)out_size; (void)ws_size;
    const float* x = (const float*)d_in[0];   // (32,128,256)
    const float* W = (const float*)d_in[1];   // (1536,256)

    float* out = (float*)d_out;
    float* mem_out = out;                                        // 32*768*768
    float* keys_out = out + (size_t)BDIM * HID * HID;            // 32*128*768
    float* vals_out = keys_out + (size_t)BDIM * TDIM * HID;      // 32*128*768

    // workspace: i_buf 12.6MB | Cbf 1.05MB | 4x bf16 6.29MB each = ~38.8MB
    float* i_buf = (float*)d_ws;                                 // (B*T, 768) f32 value half
    unsigned short* Cbf = (unsigned short*)(i_buf + (size_t)BDIM * TDIM * HID);
    unsigned short* keys_bf = Cbf + (size_t)BDIM * TDIM * TDIM;  // (B*T, H)
    unsigned short* ktr_bf = keys_bf + (size_t)BDIM * TDIM * HID;
    unsigned short* ktrT = ktr_bf + (size_t)BDIM * TDIM * HID;   // (B, H, T)
    unsigned short* vtrT = ktrT + (size_t)BDIM * HID * TDIM;     // (B, H, T)

    hipLaunchKernelGGL(k1_fused, dim3(32, 12), dim3(256), 0, stream,
                       x, W, i_buf, keys_out, keys_bf, ktr_bf, ktrT);
    hipLaunchKernelGGL(k3_mfma, dim3(2, 32), dim3(256), 0, stream, keys_bf, ktr_bf, Cbf);
    hipLaunchKernelGGL(k4_value, dim3(12, 32), dim3(64), 0, stream, i_buf, Cbf, vals_out, vtrT);
    hipLaunchKernelGGL(k5_mfma, dim3(6, 6, 32), dim3(256), 0, stream, vtrT, ktrT, mem_out);
}

// Round 10
// 194.428 us; speedup vs baseline: 2.6233x; 1.0054x over previous
//
#include <hip/hip_runtime.h>
#include <math.h>

#define BDIM 32
#define TDIM 128
#define HID 768
#define INP 256

#define ALPHA_F 0.9512294245007140f
#define DECAY_F 0.9512294245007140f
#define ETA_F 0.1f
#define IKV_SCALE 0.02f

typedef __attribute__((ext_vector_type(8))) short bf16x8;
typedef __attribute__((ext_vector_type(4))) float f32x4_t;

__device__ inline unsigned short f2bf(float f) {
    unsigned int u = __builtin_bit_cast(unsigned int, f);
    u += 0x7fffu + ((u >> 16) & 1u);      // round-to-nearest-even
    return (unsigned short)(u >> 16);
}

__device__ inline float bf2f(unsigned short us) {
    unsigned int ui = ((unsigned int)us) << 16;
    return __builtin_bit_cast(float, ui);
}

__device__ inline bf16x8 pack2(float4 a, float4 b) {
    bf16x8 r;
    r[0] = (short)f2bf(a.x); r[1] = (short)f2bf(a.y);
    r[2] = (short)f2bf(a.z); r[3] = (short)f2bf(a.w);
    r[4] = (short)f2bf(b.x); r[5] = (short)f2bf(b.y);
    r[6] = (short)f2bf(b.z); r[7] = (short)f2bf(b.w);
    return r;
}

// ---------------------------------------------------------------------------
// K1 (fused GEMM + key recurrence). Unchanged from R9 (verified).
// ---------------------------------------------------------------------------
__global__ __launch_bounds__(256) void k1_fused(const float* __restrict__ X,
                                                const float* __restrict__ W,
                                                float* __restrict__ i_buf,
                                                float* __restrict__ keys,
                                                unsigned short* __restrict__ keys_bf,
                                                unsigned short* __restrict__ ktr_bf,
                                                unsigned short* __restrict__ ktrT) {
    __shared__ __align__(16) float Ts[128 * 132];   // 67.6 KB; As/Bs overlay
    short* As = (short*)Ts;                          // 128x32 bf16, 64B rows
    short* Bs = As + 128 * 32;
    const int tid = threadIdx.x;
    const int lane = tid & 63;
    const int wid = tid >> 6;
    const int wm = wid >> 1, wn = wid & 1;
    const int b = blockIdx.x;
    const int r0 = b * 128, n0 = blockIdx.y * 128;
    const int fr = lane & 15, q4 = lane >> 4;

    const int srow = tid >> 1;          // 0..127
    const int shalf = tid & 1;          // 16-float half
    const float* ax = &X[(size_t)(r0 + srow) * INP + shalf * 16];
    const float* bw = &W[(size_t)(n0 + srow) * INP + shalf * 16];
    const int swz = (srow & 3) << 4;
    char* asw = (char*)As + srow * 64;
    char* bsw = (char*)Bs + srow * 64;

    f32x4_t zz = {0.f, 0.f, 0.f, 0.f};
    f32x4_t acc[4][4];
#pragma unroll
    for (int m = 0; m < 4; ++m)
#pragma unroll
        for (int n = 0; n < 4; ++n) acc[m][n] = zz;

    float4 ra[4], rb[4];
#pragma unroll
    for (int q = 0; q < 4; ++q) {
        ra[q] = *(const float4*)(ax + q * 4);
        rb[q] = *(const float4*)(bw + q * 4);
    }

    for (int kt = 0; kt < 8; ++kt) {
        *(bf16x8*)(asw + (((shalf * 32) ^ swz)))      = pack2(ra[0], ra[1]);
        *(bf16x8*)(asw + (((shalf * 32 + 16) ^ swz))) = pack2(ra[2], ra[3]);
        *(bf16x8*)(bsw + (((shalf * 32) ^ swz)))      = pack2(rb[0], rb[1]);
        *(bf16x8*)(bsw + (((shalf * 32 + 16) ^ swz))) = pack2(rb[2], rb[3]);
        __syncthreads();
        if (kt < 7) {
#pragma unroll
            for (int q = 0; q < 4; ++q) {
                ra[q] = *(const float4*)(ax + (kt + 1) * 32 + q * 4);
                rb[q] = *(const float4*)(bw + (kt + 1) * 32 + q * 4);
            }
        }
        bf16x8 af[4], bfv[4];
#pragma unroll
        for (int m = 0; m < 4; ++m) {
            const int row = wm * 64 + m * 16 + fr;
            af[m] = *(const bf16x8*)((const char*)As + row * 64 + ((q4 * 16) ^ ((row & 3) << 4)));
        }
#pragma unroll
        for (int n = 0; n < 4; ++n) {
            const int row = wn * 64 + n * 16 + fr;
            bfv[n] = *(const bf16x8*)((const char*)Bs + row * 64 + ((q4 * 16) ^ ((row & 3) << 4)));
        }
#pragma unroll
        for (int m = 0; m < 4; ++m)
#pragma unroll
            for (int n = 0; n < 4; ++n)
                acc[m][n] = __builtin_amdgcn_mfma_f32_16x16x32_bf16(af[m], bfv[n], acc[m][n], 0, 0, 0);
        __syncthreads();
    }

    if (n0 < HID) {
        // ---- key block: transpose acc -> Ts, then recurrence per column
#pragma unroll
        for (int m = 0; m < 4; ++m)
#pragma unroll
            for (int n = 0; n < 4; ++n)
#pragma unroll
                for (int r = 0; r < 4; ++r)
                    Ts[(wm * 64 + m * 16 + q4 * 4 + r) * 132 + wn * 64 + n * 16 + fr] = acc[m][n][r];
        __syncthreads();
        if (tid < 128) {
            const int h = n0 + tid;
            float* kb = keys + (size_t)r0 * HID + h;
            unsigned short* kbf = keys_bf + (size_t)r0 * HID + h;
            unsigned short* tbf = ktr_bf + (size_t)r0 * HID + h;
            unsigned short* ktT = ktrT + ((size_t)b * HID + h) * TDIM;
            float kv = 0.f, kt = 0.f;
            for (int t0 = 0; t0 < TDIM; t0 += 8) {
                bf16x8 kp;
#pragma unroll
                for (int q = 0; q < 8; ++q) {
                    const int t = t0 + q;
                    const float ik = Ts[t * 132 + tid];
                    kv = ALPHA_F * kv + (1.f - ALPHA_F) * ik;
                    const float ko = tanhf(kv);
                    kb[(size_t)t * HID] = ko;
                    kbf[(size_t)t * HID] = f2bf(ko);
                    kt = DECAY_F * kt + (1.f - DECAY_F) * ko;
                    tbf[(size_t)t * HID] = f2bf(kt);
                    kp[q] = (short)f2bf(kt);
                }
                *(bf16x8*)(ktT + t0) = kp;
            }
        }
    } else {
        // ---- value block: write slim i_buf
        const int c0 = n0 - HID;
#pragma unroll
        for (int m = 0; m < 4; ++m)
#pragma unroll
            for (int n = 0; n < 4; ++n)
#pragma unroll
                for (int r = 0; r < 4; ++r)
                    i_buf[(size_t)(r0 + wm * 64 + m * 16 + q4 * 4 + r) * HID
                          + c0 + wn * 64 + n * 16 + fr] = acc[m][n][r];
    }
}

// ---------------------------------------------------------------------------
// K3 v2 (MFMA): C[b][t][s] = sum_h keys[t][h]*ktr[s][h]; bf16 out.
// One block per (t-quarter, b): 32(t) x 128(s) tile -> 128 blocks (2x the
// parallelism of the 64-block version). 4 waves as 2(m-half) x 2(n-half),
// wave tile 16x64. LDS 10 KB.
// ---------------------------------------------------------------------------
__global__ __launch_bounds__(256) void k3_mfma(const unsigned short* __restrict__ keys_bf,
                                               const unsigned short* __restrict__ ktr_bf,
                                               unsigned short* __restrict__ Cbf) {
    __shared__ short Ak[32 * 32];       // 2 KB, 64 B rows
    __shared__ short Bk[128 * 32];      // 8 KB, 64 B rows
    const int tq = blockIdx.x;          // t quarter (0..3)
    const int b = blockIdx.y;
    const int tid = threadIdx.x;
    const int lane = tid & 63;
    const int wid = tid >> 6;
    const int wm = wid >> 1, wn = wid & 1;
    const int fr = lane & 15, q4 = lane >> 4;

    const int arow = tid >> 2, aq = tid & 3;       // A: 32 rows x 4 chunks (tid<128)
    const int brow = tid >> 1, bh = tid & 1;       // B: 128 rows x 2x(16+16)B
    const unsigned short* gk = keys_bf + ((size_t)b * TDIM + tq * 32 + arow) * HID + aq * 8;
    const unsigned short* gt = ktr_bf + ((size_t)b * TDIM + brow) * HID + bh * 16;
    char* akw = (char*)Ak + arow * 64;
    char* bkw = (char*)Bk + brow * 64;
    const int aswz = (arow & 3) << 4, bswz = (brow & 3) << 4;

    f32x4_t zz = {0.f, 0.f, 0.f, 0.f};
    f32x4_t acc[4];
#pragma unroll
    for (int n = 0; n < 4; ++n) acc[n] = zz;

    bf16x8 pk;
    if (tid < 128) pk = *(const bf16x8*)gk;
    bf16x8 pt0 = *(const bf16x8*)gt;
    bf16x8 pt1 = *(const bf16x8*)(gt + 8);

    for (int kt = 0; kt < 24; ++kt) {
        if (tid < 128) *(bf16x8*)(akw + ((aq * 16) ^ aswz)) = pk;
        *(bf16x8*)(bkw + ((bh * 32) ^ bswz)) = pt0;
        *(bf16x8*)(bkw + ((bh * 32 + 16) ^ bswz)) = pt1;
        __syncthreads();
        if (kt < 23) {
            if (tid < 128) pk = *(const bf16x8*)(gk + (kt + 1) * 32);
            pt0 = *(const bf16x8*)(gt + (kt + 1) * 32);
            pt1 = *(const bf16x8*)(gt + (kt + 1) * 32 + 8);
        }
        bf16x8 af, bfv[4];
        {
            const int row = wm * 16 + fr;
            af = *(const bf16x8*)((const char*)Ak + row * 64 + ((q4 * 16) ^ ((row & 3) << 4)));
        }
#pragma unroll
        for (int n = 0; n < 4; ++n) {
            const int row = wn * 64 + n * 16 + fr;
            bfv[n] = *(const bf16x8*)((const char*)Bk + row * 64 + ((q4 * 16) ^ ((row & 3) << 4)));
        }
#pragma unroll
        for (int n = 0; n < 4; ++n)
            acc[n] = __builtin_amdgcn_mfma_f32_16x16x32_bf16(af, bfv[n], acc[n], 0, 0, 0);
        __syncthreads();
    }
#pragma unroll
    for (int n = 0; n < 4; ++n)
#pragma unroll
        for (int r = 0; r < 4; ++r) {
            const int t = tq * 32 + wm * 16 + q4 * 4 + r;
            const int s = wn * 64 + n * 16 + fr;
            Cbf[((size_t)b * TDIM + t) * TDIM + s] = f2bf(acc[n][r]);
        }
}

// ---------------------------------------------------------------------------
// K4 v4: tiled value recurrence, dense phase on MFMA. Unchanged from R9.
// ---------------------------------------------------------------------------
__global__ __launch_bounds__(64) void k4_value(const float* __restrict__ IV,
                                               const unsigned short* __restrict__ Cbf,
                                               float* __restrict__ vals,
                                               unsigned short* __restrict__ vtrT) {
    __shared__ __align__(16) unsigned short Cs[128 * 136];    // 34.8 KB, 272B rows
    __shared__ __align__(16) unsigned short histb[64 * 104];  // 13.3 KB, 208B rows
    __shared__ float CdT[32 * 32];                            // 4 KB
    __shared__ float pre_s[32 * 68];                          // 8.7 KB
    const int b = blockIdx.y;
    const int h0 = blockIdx.x * 64;
    const int j = threadIdx.x;          // 0..63
    const int fr = j & 15, q4 = j >> 4;

    // stage C[b] (bf16): rows j and j+64
    {
        const unsigned short* Cb = Cbf + (size_t)b * TDIM * TDIM;
#pragma unroll
        for (int rr = 0; rr < 2; ++rr) {
            const int r = j + rr * 64;
#pragma unroll
            for (int s8 = 0; s8 < 16; ++s8)
                *(bf16x8*)((char*)Cs + r * 272 + s8 * 16) =
                    *(const bf16x8*)(Cb + r * TDIM + s8 * 8);
        }
    }
    __syncthreads();

    const float* Ibase = IV + (size_t)b * TDIM * HID + h0 + j;
    float* vals_base = vals + (size_t)b * TDIM * HID + h0 + j;
    unsigned short* vT = vtrT + ((size_t)b * HID + h0 + j) * TDIM;

    float vv = 0.f, vtr_c = 0.f;
    f32x4_t zz = {0.f, 0.f, 0.f, 0.f};

    for (int tile = 0; tile < 4; ++tile) {
        const int t0 = tile * 32;

        // ---- stage CdT[u][tt] = (tt>u) ? C[t0+tt][t0+u] : 0  (fp32)
#pragma unroll
        for (int q = 0; q < 16; ++q) {
            const int e = j * 16 + q;
            const int u = e >> 5, tt = e & 31;
            float v = 0.f;
            if (tt > u)
                v = bf2f(*(const unsigned short*)((const char*)Cs + (t0 + tt) * 272 + (t0 + u) * 2));
            CdT[u * 32 + tt] = v;
        }

        // ---- prefetch iv (independent global loads)
        float ivp[32];
#pragma unroll
        for (int u = 0; u < 32; ++u) ivp[u] = Ibase[(size_t)(t0 + u) * HID];

        // ---- dense phase via MFMA: pre_s[tt][h] = sum_{s<t0} C[t0+tt][s]*hist[h][s]
        if (tile > 0) {
            f32x4_t accd[2][4];
#pragma unroll
            for (int mt = 0; mt < 2; ++mt)
#pragma unroll
                for (int nt = 0; nt < 4; ++nt) accd[mt][nt] = zz;
            for (int kc = 0; kc < tile; ++kc) {
                bf16x8 afr[2], bfr[4];
#pragma unroll
                for (int mt = 0; mt < 2; ++mt)
                    afr[mt] = *(const bf16x8*)((const char*)Cs
                              + (size_t)(t0 + mt * 16 + fr) * 272 + kc * 64 + q4 * 16);
#pragma unroll
                for (int nt = 0; nt < 4; ++nt)
                    bfr[nt] = *(const bf16x8*)((const char*)histb
                              + (size_t)(nt * 16 + fr) * 208 + kc * 64 + q4 * 16);
#pragma unroll
                for (int mt = 0; mt < 2; ++mt)
#pragma unroll
                    for (int nt = 0; nt < 4; ++nt)
                        accd[mt][nt] = __builtin_amdgcn_mfma_f32_16x16x32_bf16(afr[mt], bfr[nt], accd[mt][nt], 0, 0, 0);
            }
#pragma unroll
            for (int mt = 0; mt < 2; ++mt)
#pragma unroll
                for (int nt = 0; nt < 4; ++nt)
#pragma unroll
                    for (int r = 0; r < 4; ++r)
                        pre_s[(mt * 16 + q4 * 4 + r) * 68 + nt * 16 + fr] = accd[mt][nt][r];
        }
        __syncthreads();   // CdT + pre_s visible

        float pre[32];
        if (tile > 0) {
#pragma unroll
            for (int tt = 0; tt < 32; ++tt) pre[tt] = pre_s[tt * 68 + j];
        } else {
#pragma unroll
            for (int tt = 0; tt < 32; ++tt) pre[tt] = 0.f;
        }

        // ---- serial phase: 32 steps, scatter-on-write
        unsigned short vb[32];
#pragma unroll
        for (int u = 0; u < 32; ++u) {
            vv = ALPHA_F * vv + (1.f - ALPHA_F) * (ivp[u] + IKV_SCALE * pre[u]);
            const float val = tanhf(vv);
            vtr_c = DECAY_F * vtr_c + (1.f - DECAY_F) * val;
            vals_base[(size_t)(t0 + u) * HID] = val;
            const unsigned short vbf = f2bf(vtr_c);
            vb[u] = vbf;
            if (tile < 3) histb[j * 104 + t0 + u] = vbf;   // own row, no race
#pragma unroll
            for (int c = 0; c < 8; ++c) {
                float4 cd = *(const float4*)&CdT[u * 32 + c * 4];   // broadcast
                pre[c * 4 + 0] += cd.x * vtr_c;
                pre[c * 4 + 1] += cd.y * vtr_c;
                pre[c * 4 + 2] += cd.z * vtr_c;
                pre[c * 4 + 3] += cd.w * vtr_c;
            }
        }
#pragma unroll
        for (int q8 = 0; q8 < 4; ++q8) {
            bf16x8 p;
#pragma unroll
            for (int c = 0; c < 8; ++c) p[c] = (short)vb[q8 * 8 + c];
            *(bf16x8*)(vT + t0 + q8 * 8) = p;
        }
        __syncthreads();   // hist/pre_s/CdT safe to rewrite next tile
    }
}

// ---------------------------------------------------------------------------
// K5 v2 (MFMA): mem[b][i][j] = ETA * sum_t vtrT[i][t] * ktrT[j][t].
// LDS-staged: A/B tiles are CONTIGUOUS 32 KB in the [h][t] layout -> fully
// coalesced bf16x8 global loads (vs 16B/256B-stride gathers before), then
// MFMA fragments from swizzled LDS (2-way conflicts max).
// ---------------------------------------------------------------------------
__global__ __launch_bounds__(256) void k5_mfma(const unsigned short* __restrict__ vtrT,
                                               const unsigned short* __restrict__ ktrT,
                                               float* __restrict__ mem) {
    __shared__ __align__(16) unsigned short Va[128 * 128];   // 32 KB, 256B rows, swizzled
    __shared__ __align__(16) unsigned short Kb[128 * 128];   // 32 KB
    const int b = blockIdx.z;
    const int i0 = blockIdx.y * 128;
    const int j0 = blockIdx.x * 128;
    const int tid = threadIdx.x;
    const int lane = tid & 63;
    const int wid = tid >> 6;
    const int wm = wid >> 1, wn = wid & 1;
    const int fr = lane & 15, q4 = lane >> 4;

    // stage: row = h-index, 16 x 16B chunks per row, 2 threads per row
    {
        const unsigned short* Ag = vtrT + ((size_t)b * HID + i0) * TDIM;
        const unsigned short* Bg = ktrT + ((size_t)b * HID + j0) * TDIM;
        const int row = tid >> 1;
        const int cbase = (tid & 1) * 8;
        const int rsw = (row & 7) << 4;
#pragma unroll
        for (int cc = 0; cc < 8; ++cc) {
            const int c = cbase + cc;
            bf16x8 va = *(const bf16x8*)(Ag + (size_t)row * TDIM + c * 8);
            bf16x8 kb = *(const bf16x8*)(Bg + (size_t)row * TDIM + c * 8);
            *(bf16x8*)((char*)Va + row * 256 + ((c * 16) ^ rsw)) = va;
            *(bf16x8*)((char*)Kb + row * 256 + ((c * 16) ^ rsw)) = kb;
        }
    }
    __syncthreads();

    f32x4_t zz = {0.f, 0.f, 0.f, 0.f};
    f32x4_t acc[4][4];
#pragma unroll
    for (int m = 0; m < 4; ++m)
#pragma unroll
        for (int n = 0; n < 4; ++n) acc[m][n] = zz;

#pragma unroll
    for (int kt = 0; kt < 4; ++kt) {
        bf16x8 af[4], bfv[4];
        const int fsw = (fr & 7) << 4;
#pragma unroll
        for (int m = 0; m < 4; ++m) {
            const int row = wm * 64 + m * 16 + fr;
            af[m] = *(const bf16x8*)((const char*)Va + row * 256 + ((kt * 64 + q4 * 16) ^ fsw));
        }
#pragma unroll
        for (int n = 0; n < 4; ++n) {
            const int row = wn * 64 + n * 16 + fr;
            bfv[n] = *(const bf16x8*)((const char*)Kb + row * 256 + ((kt * 64 + q4 * 16) ^ fsw));
        }
#pragma unroll
        for (int m = 0; m < 4; ++m)
#pragma unroll
            for (int n = 0; n < 4; ++n)
                acc[m][n] = __builtin_amdgcn_mfma_f32_16x16x32_bf16(af[m], bfv[n], acc[m][n], 0, 0, 0);
    }
#pragma unroll
    for (int m = 0; m < 4; ++m)
#pragma unroll
        for (int n = 0; n < 4; ++n)
#pragma unroll
            for (int r = 0; r < 4; ++r)
                mem[((size_t)b * HID + i0 + wm * 64 + m * 16 + q4 * 4 + r) * HID
                    + j0 + wn * 64 + n * 16 + fr] = ETA_F * acc[m][n][r];
}

// ---------------------------------------------------------------------------
extern "C" void kernel_launch(void* const* d_in, const int* in_sizes, int n_in,
                              void* d_out, int out_size, void* d_ws, size_t ws_size,
                              hipStream_t stream) {
    (void)in_sizes; (void)n_in; (void)out_size; (void)ws_size;
    const float* x = (const float*)d_in[0];   // (32,128,256)
    const float* W = (const float*)d_in[1];   // (1536,256)

    float* out = (float*)d_out;
    float* mem_out = out;                                        // 32*768*768
    float* keys_out = out + (size_t)BDIM * HID * HID;            // 32*128*768
    float* vals_out = keys_out + (size_t)BDIM * TDIM * HID;      // 32*128*768

    // workspace: i_buf 12.6MB | Cbf 1.05MB | 4x bf16 6.29MB each = ~38.8MB
    float* i_buf = (float*)d_ws;                                 // (B*T, 768) f32 value half
    unsigned short* Cbf = (unsigned short*)(i_buf + (size_t)BDIM * TDIM * HID);
    unsigned short* keys_bf = Cbf + (size_t)BDIM * TDIM * TDIM;  // (B*T, H)
    unsigned short* ktr_bf = keys_bf + (size_t)BDIM * TDIM * HID;
    unsigned short* ktrT = ktr_bf + (size_t)BDIM * TDIM * HID;   // (B, H, T)
    unsigned short* vtrT = ktrT + (size_t)BDIM * HID * TDIM;     // (B, H, T)

    hipLaunchKernelGGL(k1_fused, dim3(32, 12), dim3(256), 0, stream,
                       x, W, i_buf, keys_out, keys_bf, ktr_bf, ktrT);
    hipLaunchKernelGGL(k3_mfma, dim3(4, 32), dim3(256), 0, stream, keys_bf, ktr_bf, Cbf);
    hipLaunchKernelGGL(k4_value, dim3(12, 32), dim3(64), 0, stream, i_buf, Cbf, vals_out, vtrT);
    hipLaunchKernelGGL(k5_mfma, dim3(6, 6, 32), dim3(256), 0, stream, vtrT, ktrT, mem_out);
}

// Round 11
// 182.708 us; speedup vs baseline: 2.7916x; 1.0641x over previous
//
#include <hip/hip_runtime.h>
#include <math.h>

#define BDIM 32
#define TDIM 128
#define HID 768
#define INP 256

#define ALPHA_F 0.9512294245007140f
#define DECAY_F 0.9512294245007140f
#define ETA_F 0.1f
#define IKV_SCALE 0.02f

typedef __attribute__((ext_vector_type(8))) short bf16x8;
typedef __attribute__((ext_vector_type(4))) float f32x4_t;

__device__ inline unsigned short f2bf(float f) {
    unsigned int u = __builtin_bit_cast(unsigned int, f);
    u += 0x7fffu + ((u >> 16) & 1u);      // round-to-nearest-even
    return (unsigned short)(u >> 16);
}

__device__ inline float bf2f(unsigned short us) {
    unsigned int ui = ((unsigned int)us) << 16;
    return __builtin_bit_cast(float, ui);
}

// tanh via hardware exp/rcp: (e^2x - 1) * rcp(e^2x + 1); ~6 VALU ops vs libm.
// clamp at 15: tanh(15) = 1 - 2e-13, exact 1.0f after rounding.
__device__ inline float fast_tanh(float x) {
    x = fminf(fmaxf(x, -15.f), 15.f);
    const float p = __expf(2.f * x);
    return (p - 1.f) * __builtin_amdgcn_rcpf(p + 1.f);
}

__device__ inline bf16x8 pack2(float4 a, float4 b) {
    bf16x8 r;
    r[0] = (short)f2bf(a.x); r[1] = (short)f2bf(a.y);
    r[2] = (short)f2bf(a.z); r[3] = (short)f2bf(a.w);
    r[4] = (short)f2bf(b.x); r[5] = (short)f2bf(b.y);
    r[6] = (short)f2bf(b.z); r[7] = (short)f2bf(b.w);
    return r;
}

__device__ inline void scatter8(float (&pre)[32], const float4 (&cd)[8], float v) {
#pragma unroll
    for (int c = 0; c < 8; ++c) {
        pre[c * 4 + 0] += cd[c].x * v;
        pre[c * 4 + 1] += cd[c].y * v;
        pre[c * 4 + 2] += cd[c].z * v;
        pre[c * 4 + 3] += cd[c].w * v;
    }
}

// ---------------------------------------------------------------------------
// K1 (fused GEMM + key recurrence). Unchanged except fast_tanh.
// ---------------------------------------------------------------------------
__global__ __launch_bounds__(256) void k1_fused(const float* __restrict__ X,
                                                const float* __restrict__ W,
                                                float* __restrict__ i_buf,
                                                float* __restrict__ keys,
                                                unsigned short* __restrict__ keys_bf,
                                                unsigned short* __restrict__ ktr_bf,
                                                unsigned short* __restrict__ ktrT) {
    __shared__ __align__(16) float Ts[128 * 132];   // 67.6 KB; As/Bs overlay
    short* As = (short*)Ts;                          // 128x32 bf16, 64B rows
    short* Bs = As + 128 * 32;
    const int tid = threadIdx.x;
    const int lane = tid & 63;
    const int wid = tid >> 6;
    const int wm = wid >> 1, wn = wid & 1;
    const int b = blockIdx.x;
    const int r0 = b * 128, n0 = blockIdx.y * 128;
    const int fr = lane & 15, q4 = lane >> 4;

    const int srow = tid >> 1;          // 0..127
    const int shalf = tid & 1;          // 16-float half
    const float* ax = &X[(size_t)(r0 + srow) * INP + shalf * 16];
    const float* bw = &W[(size_t)(n0 + srow) * INP + shalf * 16];
    const int swz = (srow & 3) << 4;
    char* asw = (char*)As + srow * 64;
    char* bsw = (char*)Bs + srow * 64;

    f32x4_t zz = {0.f, 0.f, 0.f, 0.f};
    f32x4_t acc[4][4];
#pragma unroll
    for (int m = 0; m < 4; ++m)
#pragma unroll
        for (int n = 0; n < 4; ++n) acc[m][n] = zz;

    float4 ra[4], rb[4];
#pragma unroll
    for (int q = 0; q < 4; ++q) {
        ra[q] = *(const float4*)(ax + q * 4);
        rb[q] = *(const float4*)(bw + q * 4);
    }

    for (int kt = 0; kt < 8; ++kt) {
        *(bf16x8*)(asw + (((shalf * 32) ^ swz)))      = pack2(ra[0], ra[1]);
        *(bf16x8*)(asw + (((shalf * 32 + 16) ^ swz))) = pack2(ra[2], ra[3]);
        *(bf16x8*)(bsw + (((shalf * 32) ^ swz)))      = pack2(rb[0], rb[1]);
        *(bf16x8*)(bsw + (((shalf * 32 + 16) ^ swz))) = pack2(rb[2], rb[3]);
        __syncthreads();
        if (kt < 7) {
#pragma unroll
            for (int q = 0; q < 4; ++q) {
                ra[q] = *(const float4*)(ax + (kt + 1) * 32 + q * 4);
                rb[q] = *(const float4*)(bw + (kt + 1) * 32 + q * 4);
            }
        }
        bf16x8 af[4], bfv[4];
#pragma unroll
        for (int m = 0; m < 4; ++m) {
            const int row = wm * 64 + m * 16 + fr;
            af[m] = *(const bf16x8*)((const char*)As + row * 64 + ((q4 * 16) ^ ((row & 3) << 4)));
        }
#pragma unroll
        for (int n = 0; n < 4; ++n) {
            const int row = wn * 64 + n * 16 + fr;
            bfv[n] = *(const bf16x8*)((const char*)Bs + row * 64 + ((q4 * 16) ^ ((row & 3) << 4)));
        }
#pragma unroll
        for (int m = 0; m < 4; ++m)
#pragma unroll
            for (int n = 0; n < 4; ++n)
                acc[m][n] = __builtin_amdgcn_mfma_f32_16x16x32_bf16(af[m], bfv[n], acc[m][n], 0, 0, 0);
        __syncthreads();
    }

    if (n0 < HID) {
        // ---- key block: transpose acc -> Ts, then recurrence per column
#pragma unroll
        for (int m = 0; m < 4; ++m)
#pragma unroll
            for (int n = 0; n < 4; ++n)
#pragma unroll
                for (int r = 0; r < 4; ++r)
                    Ts[(wm * 64 + m * 16 + q4 * 4 + r) * 132 + wn * 64 + n * 16 + fr] = acc[m][n][r];
        __syncthreads();
        if (tid < 128) {
            const int h = n0 + tid;
            float* kb = keys + (size_t)r0 * HID + h;
            unsigned short* kbf = keys_bf + (size_t)r0 * HID + h;
            unsigned short* tbf = ktr_bf + (size_t)r0 * HID + h;
            unsigned short* ktT = ktrT + ((size_t)b * HID + h) * TDIM;
            float kv = 0.f, kt = 0.f;
            for (int t0 = 0; t0 < TDIM; t0 += 8) {
                bf16x8 kp;
#pragma unroll
                for (int q = 0; q < 8; ++q) {
                    const int t = t0 + q;
                    const float ik = Ts[t * 132 + tid];
                    kv = ALPHA_F * kv + (1.f - ALPHA_F) * ik;
                    const float ko = fast_tanh(kv);
                    kb[(size_t)t * HID] = ko;
                    kbf[(size_t)t * HID] = f2bf(ko);
                    kt = DECAY_F * kt + (1.f - DECAY_F) * ko;
                    tbf[(size_t)t * HID] = f2bf(kt);
                    kp[q] = (short)f2bf(kt);
                }
                *(bf16x8*)(ktT + t0) = kp;
            }
        }
    } else {
        // ---- value block: write slim i_buf
        const int c0 = n0 - HID;
#pragma unroll
        for (int m = 0; m < 4; ++m)
#pragma unroll
            for (int n = 0; n < 4; ++n)
#pragma unroll
                for (int r = 0; r < 4; ++r)
                    i_buf[(size_t)(r0 + wm * 64 + m * 16 + q4 * 4 + r) * HID
                          + c0 + wn * 64 + n * 16 + fr] = acc[m][n][r];
    }
}

// ---------------------------------------------------------------------------
// K3 v2 (MFMA): C[b][t][s]; 32x128 tile per block, 128 blocks. Unchanged.
// ---------------------------------------------------------------------------
__global__ __launch_bounds__(256) void k3_mfma(const unsigned short* __restrict__ keys_bf,
                                               const unsigned short* __restrict__ ktr_bf,
                                               unsigned short* __restrict__ Cbf) {
    __shared__ short Ak[32 * 32];       // 2 KB, 64 B rows
    __shared__ short Bk[128 * 32];      // 8 KB, 64 B rows
    const int tq = blockIdx.x;          // t quarter (0..3)
    const int b = blockIdx.y;
    const int tid = threadIdx.x;
    const int lane = tid & 63;
    const int wid = tid >> 6;
    const int wm = wid >> 1, wn = wid & 1;
    const int fr = lane & 15, q4 = lane >> 4;

    const int arow = tid >> 2, aq = tid & 3;       // A: 32 rows x 4 chunks (tid<128)
    const int brow = tid >> 1, bh = tid & 1;       // B: 128 rows x 2x(16+16)B
    const unsigned short* gk = keys_bf + ((size_t)b * TDIM + tq * 32 + arow) * HID + aq * 8;
    const unsigned short* gt = ktr_bf + ((size_t)b * TDIM + brow) * HID + bh * 16;
    char* akw = (char*)Ak + arow * 64;
    char* bkw = (char*)Bk + brow * 64;
    const int aswz = (arow & 3) << 4, bswz = (brow & 3) << 4;

    f32x4_t zz = {0.f, 0.f, 0.f, 0.f};
    f32x4_t acc[4];
#pragma unroll
    for (int n = 0; n < 4; ++n) acc[n] = zz;

    bf16x8 pk;
    if (tid < 128) pk = *(const bf16x8*)gk;
    bf16x8 pt0 = *(const bf16x8*)gt;
    bf16x8 pt1 = *(const bf16x8*)(gt + 8);

    for (int kt = 0; kt < 24; ++kt) {
        if (tid < 128) *(bf16x8*)(akw + ((aq * 16) ^ aswz)) = pk;
        *(bf16x8*)(bkw + ((bh * 32) ^ bswz)) = pt0;
        *(bf16x8*)(bkw + ((bh * 32 + 16) ^ bswz)) = pt1;
        __syncthreads();
        if (kt < 23) {
            if (tid < 128) pk = *(const bf16x8*)(gk + (kt + 1) * 32);
            pt0 = *(const bf16x8*)(gt + (kt + 1) * 32);
            pt1 = *(const bf16x8*)(gt + (kt + 1) * 32 + 8);
        }
        bf16x8 af, bfv[4];
        {
            const int row = wm * 16 + fr;
            af = *(const bf16x8*)((const char*)Ak + row * 64 + ((q4 * 16) ^ ((row & 3) << 4)));
        }
#pragma unroll
        for (int n = 0; n < 4; ++n) {
            const int row = wn * 64 + n * 16 + fr;
            bfv[n] = *(const bf16x8*)((const char*)Bk + row * 64 + ((q4 * 16) ^ ((row & 3) << 4)));
        }
#pragma unroll
        for (int n = 0; n < 4; ++n)
            acc[n] = __builtin_amdgcn_mfma_f32_16x16x32_bf16(af, bfv[n], acc[n], 0, 0, 0);
        __syncthreads();
    }
#pragma unroll
    for (int n = 0; n < 4; ++n)
#pragma unroll
        for (int r = 0; r < 4; ++r) {
            const int t = tq * 32 + wm * 16 + q4 * 4 + r;
            const int s = wn * 64 + n * 16 + fr;
            Cbf[((size_t)b * TDIM + t) * TDIM + s] = f2bf(acc[n][r]);
        }
}

// ---------------------------------------------------------------------------
// K4 v5: tiled value recurrence. Dense phase on MFMA (as v4). Serial phase
// now has EXPLICIT 2-deep register double-buffering of CdT rows: at the top
// of step u the 8 float4 loads for row u+1 issue into the alternate buffer
// (compile-time parity after full unroll -> static register names), so the
// ~120cy LDS latency hides under step u's VALU work. vb[32] replaced by a
// packed 4xu32 rolling window to free VGPRs for the 64-reg cd buffers.
// ---------------------------------------------------------------------------
__global__ __launch_bounds__(64) void k4_value(const float* __restrict__ IV,
                                               const unsigned short* __restrict__ Cbf,
                                               float* __restrict__ vals,
                                               unsigned short* __restrict__ vtrT) {
    __shared__ __align__(16) unsigned short Cs[128 * 136];    // 34.8 KB, 272B rows
    __shared__ __align__(16) unsigned short histb[64 * 104];  // 13.3 KB, 208B rows
    __shared__ float CdT[32 * 32];                            // 4 KB
    __shared__ float pre_s[32 * 68];                          // 8.7 KB
    const int b = blockIdx.y;
    const int h0 = blockIdx.x * 64;
    const int j = threadIdx.x;          // 0..63
    const int fr = j & 15, q4 = j >> 4;

    // stage C[b] (bf16): rows j and j+64
    {
        const unsigned short* Cb = Cbf + (size_t)b * TDIM * TDIM;
#pragma unroll
        for (int rr = 0; rr < 2; ++rr) {
            const int r = j + rr * 64;
#pragma unroll
            for (int s8 = 0; s8 < 16; ++s8)
                *(bf16x8*)((char*)Cs + r * 272 + s8 * 16) =
                    *(const bf16x8*)(Cb + r * TDIM + s8 * 8);
        }
    }
    __syncthreads();

    const float* Ibase = IV + (size_t)b * TDIM * HID + h0 + j;
    float* vals_base = vals + (size_t)b * TDIM * HID + h0 + j;
    unsigned short* vT = vtrT + ((size_t)b * HID + h0 + j) * TDIM;

    float vv = 0.f, vtr_c = 0.f;
    f32x4_t zz = {0.f, 0.f, 0.f, 0.f};

    for (int tile = 0; tile < 4; ++tile) {
        const int t0 = tile * 32;

        // ---- stage CdT[u][tt] = (tt>u) ? C[t0+tt][t0+u] : 0  (fp32)
#pragma unroll
        for (int q = 0; q < 16; ++q) {
            const int e = j * 16 + q;
            const int u = e >> 5, tt = e & 31;
            float v = 0.f;
            if (tt > u)
                v = bf2f(*(const unsigned short*)((const char*)Cs + (t0 + tt) * 272 + (t0 + u) * 2));
            CdT[u * 32 + tt] = v;
        }

        // ---- prefetch iv (independent, coalesced global loads)
        float ivp[32];
#pragma unroll
        for (int u = 0; u < 32; ++u) ivp[u] = Ibase[(size_t)(t0 + u) * HID];

        // ---- dense phase via MFMA: pre_s[tt][h] = sum_{s<t0} C[t0+tt][s]*hist[h][s]
        if (tile > 0) {
            f32x4_t accd[2][4];
#pragma unroll
            for (int mt = 0; mt < 2; ++mt)
#pragma unroll
                for (int nt = 0; nt < 4; ++nt) accd[mt][nt] = zz;
            for (int kc = 0; kc < tile; ++kc) {
                bf16x8 afr[2], bfr[4];
#pragma unroll
                for (int mt = 0; mt < 2; ++mt)
                    afr[mt] = *(const bf16x8*)((const char*)Cs
                              + (size_t)(t0 + mt * 16 + fr) * 272 + kc * 64 + q4 * 16);
#pragma unroll
                for (int nt = 0; nt < 4; ++nt)
                    bfr[nt] = *(const bf16x8*)((const char*)histb
                              + (size_t)(nt * 16 + fr) * 208 + kc * 64 + q4 * 16);
#pragma unroll
                for (int mt = 0; mt < 2; ++mt)
#pragma unroll
                    for (int nt = 0; nt < 4; ++nt)
                        accd[mt][nt] = __builtin_amdgcn_mfma_f32_16x16x32_bf16(afr[mt], bfr[nt], accd[mt][nt], 0, 0, 0);
            }
#pragma unroll
            for (int mt = 0; mt < 2; ++mt)
#pragma unroll
                for (int nt = 0; nt < 4; ++nt)
#pragma unroll
                    for (int r = 0; r < 4; ++r)
                        pre_s[(mt * 16 + q4 * 4 + r) * 68 + nt * 16 + fr] = accd[mt][nt][r];
        }
        __syncthreads();   // CdT + pre_s visible

        float pre[32];
        if (tile > 0) {
#pragma unroll
            for (int tt = 0; tt < 32; ++tt) pre[tt] = pre_s[tt * 68 + j];
        } else {
#pragma unroll
            for (int tt = 0; tt < 32; ++tt) pre[tt] = 0.f;
        }

        // ---- serial phase: 32 steps, scatter-on-write, explicit cd pipeline
        float4 cda[8], cdb[8];
#pragma unroll
        for (int c = 0; c < 8; ++c) cda[c] = *(const float4*)&CdT[c * 4];   // row 0
        unsigned int vb0 = 0, vb1 = 0, vb2 = 0, vb3 = 0;
#pragma unroll
        for (int u = 0; u < 32; ++u) {
            // prefetch row u+1 into the alternate buffer (parity is
            // compile-time constant after full unroll -> static reg names)
            if (u < 31) {
                if ((u & 1) == 0) {
#pragma unroll
                    for (int c = 0; c < 8; ++c)
                        cdb[c] = *(const float4*)&CdT[(u + 1) * 32 + c * 4];
                } else {
#pragma unroll
                    for (int c = 0; c < 8; ++c)
                        cda[c] = *(const float4*)&CdT[(u + 1) * 32 + c * 4];
                }
            }
            vv = ALPHA_F * vv + (1.f - ALPHA_F) * (ivp[u] + IKV_SCALE * pre[u]);
            const float val = fast_tanh(vv);
            vtr_c = DECAY_F * vtr_c + (1.f - DECAY_F) * val;
            vals_base[(size_t)(t0 + u) * HID] = val;
            const unsigned int vbf = f2bf(vtr_c);
            if (tile < 3) histb[j * 104 + t0 + u] = (unsigned short)vbf;
            // pack vtr into rolling 8-wide window (static after unroll)
            {
                const int q8 = (u & 7) >> 1;
                const unsigned int piece = (u & 1) ? (vbf << 16) : vbf;
                if (q8 == 0) vb0 = (u & 1) ? (vb0 | piece) : piece;
                else if (q8 == 1) vb1 = (u & 1) ? (vb1 | piece) : piece;
                else if (q8 == 2) vb2 = (u & 1) ? (vb2 | piece) : piece;
                else vb3 = (u & 1) ? (vb3 | piece) : piece;
            }
            if ((u & 7) == 7) {
                uint4 pk4;
                pk4.x = vb0; pk4.y = vb1; pk4.z = vb2; pk4.w = vb3;
                *(uint4*)(vT + t0 + (u - 7)) = pk4;
            }
            if ((u & 1) == 0) scatter8(pre, cda, vtr_c);
            else              scatter8(pre, cdb, vtr_c);
        }
        __syncthreads();   // hist/pre_s/CdT safe to rewrite next tile
    }
}

// ---------------------------------------------------------------------------
// K5 v2 (MFMA): mem = ETA * vtrT @ ktrT^T per batch; LDS-staged. Unchanged.
// ---------------------------------------------------------------------------
__global__ __launch_bounds__(256) void k5_mfma(const unsigned short* __restrict__ vtrT,
                                               const unsigned short* __restrict__ ktrT,
                                               float* __restrict__ mem) {
    __shared__ __align__(16) unsigned short Va[128 * 128];   // 32 KB, 256B rows, swizzled
    __shared__ __align__(16) unsigned short Kb[128 * 128];   // 32 KB
    const int b = blockIdx.z;
    const int i0 = blockIdx.y * 128;
    const int j0 = blockIdx.x * 128;
    const int tid = threadIdx.x;
    const int lane = tid & 63;
    const int wid = tid >> 6;
    const int wm = wid >> 1, wn = wid & 1;
    const int fr = lane & 15, q4 = lane >> 4;

    {
        const unsigned short* Ag = vtrT + ((size_t)b * HID + i0) * TDIM;
        const unsigned short* Bg = ktrT + ((size_t)b * HID + j0) * TDIM;
        const int row = tid >> 1;
        const int cbase = (tid & 1) * 8;
        const int rsw = (row & 7) << 4;
#pragma unroll
        for (int cc = 0; cc < 8; ++cc) {
            const int c = cbase + cc;
            bf16x8 va = *(const bf16x8*)(Ag + (size_t)row * TDIM + c * 8);
            bf16x8 kb = *(const bf16x8*)(Bg + (size_t)row * TDIM + c * 8);
            *(bf16x8*)((char*)Va + row * 256 + ((c * 16) ^ rsw)) = va;
            *(bf16x8*)((char*)Kb + row * 256 + ((c * 16) ^ rsw)) = kb;
        }
    }
    __syncthreads();

    f32x4_t zz = {0.f, 0.f, 0.f, 0.f};
    f32x4_t acc[4][4];
#pragma unroll
    for (int m = 0; m < 4; ++m)
#pragma unroll
        for (int n = 0; n < 4; ++n) acc[m][n] = zz;

#pragma unroll
    for (int kt = 0; kt < 4; ++kt) {
        bf16x8 af[4], bfv[4];
        const int fsw = (fr & 7) << 4;
#pragma unroll
        for (int m = 0; m < 4; ++m) {
            const int row = wm * 64 + m * 16 + fr;
            af[m] = *(const bf16x8*)((const char*)Va + row * 256 + ((kt * 64 + q4 * 16) ^ fsw));
        }
#pragma unroll
        for (int n = 0; n < 4; ++n) {
            const int row = wn * 64 + n * 16 + fr;
            bfv[n] = *(const bf16x8*)((const char*)Kb + row * 256 + ((kt * 64 + q4 * 16) ^ fsw));
        }
#pragma unroll
        for (int m = 0; m < 4; ++m)
#pragma unroll
            for (int n = 0; n < 4; ++n)
                acc[m][n] = __builtin_amdgcn_mfma_f32_16x16x32_bf16(af[m], bfv[n], acc[m][n], 0, 0, 0);
    }
#pragma unroll
    for (int m = 0; m < 4; ++m)
#pragma unroll
        for (int n = 0; n < 4; ++n)
#pragma unroll
            for (int r = 0; r < 4; ++r)
                mem[((size_t)b * HID + i0 + wm * 64 + m * 16 + q4 * 4 + r) * HID
                    + j0 + wn * 64 + n * 16 + fr] = ETA_F * acc[m][n][r];
}

// ---------------------------------------------------------------------------
extern "C" void kernel_launch(void* const* d_in, const int* in_sizes, int n_in,
                              void* d_out, int out_size, void* d_ws, size_t ws_size,
                              hipStream_t stream) {
    (void)in_sizes; (void)n_in; (void)out_size; (void)ws_size;
    const float* x = (const float*)d_in[0];   // (32,128,256)
    const float* W = (const float*)d_in[1];   // (1536,256)

    float* out = (float*)d_out;
    float* mem_out = out;                                        // 32*768*768
    float* keys_out = out + (size_t)BDIM * HID * HID;            // 32*128*768
    float* vals_out = keys_out + (size_t)BDIM * TDIM * HID;      // 32*128*768

    // workspace: i_buf 12.6MB | Cbf 1.05MB | 4x bf16 6.29MB each = ~38.8MB
    float* i_buf = (float*)d_ws;                                 // (B*T, 768) f32 value half
    unsigned short* Cbf = (unsigned short*)(i_buf + (size_t)BDIM * TDIM * HID);
    unsigned short* keys_bf = Cbf + (size_t)BDIM * TDIM * TDIM;  // (B*T, H)
    unsigned short* ktr_bf = keys_bf + (size_t)BDIM * TDIM * HID;
    unsigned short* ktrT = ktr_bf + (size_t)BDIM * TDIM * HID;   // (B, H, T)
    unsigned short* vtrT = ktrT + (size_t)BDIM * HID * TDIM;     // (B, H, T)

    hipLaunchKernelGGL(k1_fused, dim3(32, 12), dim3(256), 0, stream,
                       x, W, i_buf, keys_out, keys_bf, ktr_bf, ktrT);
    hipLaunchKernelGGL(k3_mfma, dim3(4, 32), dim3(256), 0, stream, keys_bf, ktr_bf, Cbf);
    hipLaunchKernelGGL(k4_value, dim3(12, 32), dim3(64), 0, stream, i_buf, Cbf, vals_out, vtrT);
    hipLaunchKernelGGL(k5_mfma, dim3(6, 6, 32), dim3(256), 0, stream, vtrT, ktrT, mem_out);
}